// Round 10
// baseline (937.461 us; speedup 1.0000x reference)
//
#include <hip/hip_runtime.h>
#include <hip/hip_bf16.h>
#include <math.h>

#define B_ 32
#define L_ 128
#define LP 130      // padded L (zero row before/after each batch)
#define E_ 300
#define EP 320      // padded E (%64)
#define H_ 512
#define DOUT_ 5
#define NSTEP 5
#define G7 3584     // 7H
#define KGATES 2368 // 1536 (hl|h|hr from hpad) + 512 (g) + 320 (x padded)
#define KFI 1024    // 512 (g) + 512 (h)

typedef __hip_bfloat16 bf16;
using bf16x8 = __attribute__((ext_vector_type(8))) __bf16;
using f32x4 = __attribute__((ext_vector_type(4))) float;

__device__ __forceinline__ void gload16(const void* g, void* l) {
  __builtin_amdgcn_global_load_lds(
      (const __attribute__((address_space(1))) void*)g,
      (__attribute__((address_space(3))) void*)l, 16, 0, 0);
}

// ---------------- small helpers ----------------
__global__ void fill_zero(float* __restrict__ p, int n) {
  int i = blockIdx.x * blockDim.x + threadIdx.x;
  if (i < n) p[i] = 0.f;
}

__global__ void mask_lens_kernel(const int* __restrict__ lengths,
                                 float* __restrict__ maskf,
                                 float* __restrict__ invlens) {
  int i = blockIdx.x * blockDim.x + threadIdx.x;
  if (i < B_ * L_) {
    int b = i >> 7, l = i & 127;
    maskf[i] = (l < lengths[b]) ? 1.f : 0.f;
    if (l == 0) invlens[b] = 1.f / fmaxf((float)lengths[b], 1.f);
  }
}

__global__ void embed_bf16_kernel(const int* __restrict__ tokens,
                                  const float* __restrict__ embed,
                                  bf16* __restrict__ xb) {
  int i = blockIdx.x * blockDim.x + threadIdx.x;  // B*L*EP
  if (i >= B_ * L_ * EP) return;
  int e = i % EP, bl = i / EP;
  float v = (e < E_) ? embed[(size_t)tokens[bl] * E_ + e] : 0.f;
  xb[i] = __float2bfloat16(v);
}

__global__ void fill_pad(bf16* __restrict__ hpad) {
  int i = blockIdx.x * blockDim.x + threadIdx.x;  // B*2*H
  if (i >= B_ * 2 * H_) return;
  int hh = i & (H_ - 1);
  int r = (i >> 9) & 1, b = i >> 10;
  hpad[((size_t)(b * LP + r * (LP - 1))) * H_ + hh] = __float2bfloat16(0.f);
}

// transpose + cast: Wt[n][k] = W[k][n]; grid (Kregion/64, Ncols/64).
__global__ __launch_bounds__(256) void transpose_to_bf16(
    const float* __restrict__ W, bf16* __restrict__ Wt, int Kreal, int Ncols,
    int dstStride) {
  __shared__ float tile[64][65];
  const int k0 = blockIdx.x * 64, n0 = blockIdx.y * 64;
  const int t = threadIdx.x;
  const int nn = t & 63, kk0 = t >> 6;
#pragma unroll
  for (int p = 0; p < 16; ++p) {
    int kk = kk0 + p * 4;
    int gk = k0 + kk;
    tile[kk][nn] = (gk < Kreal) ? W[(size_t)gk * Ncols + n0 + nn] : 0.f;
  }
  __syncthreads();
#pragma unroll
  for (int p = 0; p < 2; ++p) {
    int r = (t >> 3) + p * 32;
    int kb = (t & 7) * 8;
    union { ushort h[8]; uint4 v; } u;
#pragma unroll
    for (int e = 0; e < 8; ++e) {
      bf16 b = __float2bfloat16(tile[kb + e][r]);
      u.h[e] = *(ushort*)&b;
    }
    *(uint4*)&Wt[(size_t)(n0 + r) * dstStride + k0 + kb] = u.v;
  }
}

// ---------------- bf16 MFMA GEMM, 128x128 tile, BK=64 ------------------------
// LDS layout per matrix: [128 rows][8 chunks of 8 bf16], chunk XOR-swizzled
// (phys = logical ^ (row&7)); staging fetches inverse-swizzled global chunk.
// AMAP 0: A linear [M][KP].
// AMAP 2: gates A: k<1536 hpad rows (b*130+l ..+2); [1536,2048) G2[b];
//         [2048,2368) X3[row] (KP=2368).
// OUTMODE 3: bf16 into hpad (+1 row), act/rowscale.
// OUTMODE 5: bf16 fragment-permuted: idx = ((row>>2)*N+col)*4 + (row&3).
template <int AMAP, int OUTMODE>
__global__ __launch_bounds__(256) void gemm_mfma(
    const bf16* __restrict__ A, const bf16* __restrict__ G2,
    const bf16* __restrict__ X3, const bf16* __restrict__ Bt,
    const float* __restrict__ bias, const float* __restrict__ rowscale,
    void* __restrict__ Cout, int N, int KP, int act) {
  __shared__ ushort As[128 * 64];
  __shared__ ushort Bs[128 * 64];
  const int tid = threadIdx.x;
  const int lane = tid & 63;
  const int w = tid >> 6;
  const int wr = w >> 1, wc = w & 1;
  // XCD-aware bijective block swizzle (grids %8==0); keeps A rows XCD-local
  const int nbx = gridDim.x;
  const int nwg = nbx * gridDim.y;
  int id = blockIdx.y * nbx + blockIdx.x;
  if ((nwg & 7) == 0) { int q = nwg >> 3; id = (id & 7) * q + (id >> 3); }
  const int bxi = id % nbx, byi = id / nbx;
  const int rowBase = byi * 128, colBase = bxi * 128;
  const int l15 = lane & 15, l4 = lane >> 4;
  f32x4 acc[4][4] = {};

  // staging slots: c = tid + 256*i -> row c>>3, phys chunk c&7
  const bf16* bP[4];
  const bf16* aP[4];
  const bf16* gP[4];
  const bf16* xP[4];
#pragma unroll
  for (int i = 0; i < 4; ++i) {
    int c = tid + 256 * i;
    int r = c >> 3;
    int ql = (c & 7) ^ (r & 7);  // inverse-swizzled logical chunk
    bP[i] = Bt + (size_t)(colBase + r) * KP + ql * 8;
    if constexpr (AMAP == 0) {
      aP[i] = A + (size_t)(rowBase + r) * KP + ql * 8;
    } else {
      const int b = rowBase >> 7;  // BM=128 aligns with L: one batch per block
      aP[i] = A + ((size_t)(b * LP + r)) * H_ + ql * 8;       // hpad region
      gP[i] = G2 + (size_t)b * H_ + ql * 8;                   // g region
      xP[i] = X3 + (size_t)(rowBase + r) * EP + ql * 8;       // x region
    }
  }

  auto step_ = [&](const bf16* const* ap, int ko, int kb) {
#pragma unroll
    for (int i = 0; i < 4; ++i) {
      gload16(ap[i] + ko, &As[(tid + 256 * i) * 8]);
      gload16(bP[i] + kb, &Bs[(tid + 256 * i) * 8]);
    }
    __syncthreads();
#pragma unroll
    for (int kh = 0; kh < 2; ++kh) {
      bf16x8 aF[4], bF[4];
#pragma unroll
      for (int m = 0; m < 4; ++m) {
        int row = wr * 64 + m * 16 + l15;
        aF[m] = *(const bf16x8*)&As[row * 64 +
                                    (((kh << 2) + l4) ^ (l15 & 7)) * 8];
      }
#pragma unroll
      for (int n = 0; n < 4; ++n) {
        int row = wc * 64 + n * 16 + l15;
        bF[n] = *(const bf16x8*)&Bs[row * 64 +
                                    (((kh << 2) + l4) ^ (l15 & 7)) * 8];
      }
#pragma unroll
      for (int m = 0; m < 4; ++m)
#pragma unroll
        for (int n = 0; n < 4; ++n)
          acc[m][n] = __builtin_amdgcn_mfma_f32_16x16x32_bf16(
              aF[m], bF[n], acc[m][n], 0, 0, 0);
    }
    __syncthreads();
  };

  if constexpr (AMAP == 0) {
    const int nIter = KP >> 6;
    for (int t = 0; t < nIter; ++t) step_(aP, t * 64, t * 64);
  } else {
    for (int t = 0; t < 24; ++t) step_(aP, t * 64, t * 64);
    for (int t = 24; t < 32; ++t) step_(gP, (t - 24) * 64, t * 64);
    for (int t = 32; t < 37; ++t) step_(xP, (t - 32) * 64, t * 64);
  }

#pragma unroll
  for (int m = 0; m < 4; ++m) {
#pragma unroll
    for (int n = 0; n < 4; ++n) {
      int col = colBase + wc * 64 + n * 16 + l15;
      float bv = bias[col];
      if constexpr (OUTMODE == 5) {
        bf16 tmp[4];
#pragma unroll
        for (int j = 0; j < 4; ++j)
          tmp[j] = __float2bfloat16(acc[m][n][j] + bv);
        int row0 = rowBase + wr * 64 + m * 16 + l4 * 4;
        *(uint2*)&((bf16*)Cout)[((size_t)(row0 >> 2) * N + col) * 4] =
            *(uint2*)tmp;
      } else {  // OUTMODE == 3
#pragma unroll
        for (int j = 0; j < 4; ++j) {
          int row = rowBase + wr * 64 + m * 16 + l4 * 4 + j;
          float v = acc[m][n][j] + bv;
          if (act == 1) v = tanhf(v);
          v *= rowscale[row];
          size_t oi = ((size_t)((row >> 7) * LP + (row & 127) + 1)) * H_ + col;
          ((bf16*)Cout)[oi] = __float2bfloat16(v);
        }
      }
    }
  }
}

// ---------------- fused fi GEMM + slot softmax update (BK=64) ---------------
__global__ __launch_bounds__(256) void fi_slot_kernel(
    const bf16* __restrict__ gcur, const bf16* __restrict__ hpad,
    const bf16* __restrict__ Wfit, const float* __restrict__ bfi,
    const float* __restrict__ fg, const float* __restrict__ og,
    const float* __restrict__ c_new, const float* __restrict__ cg_old,
    const float* __restrict__ maskf, float* __restrict__ cg_new,
    float* __restrict__ g_new, bf16* __restrict__ gcur_new) {
  __shared__ __align__(16) char smem[128 * 129 * 4 + 3072];  // 69120 B
  ushort* As = (ushort*)smem;                  // [128*64], dead after K-loop
  ushort* Bs = As + 128 * 64;
  float* sfi = (float*)smem;                   // [128 cols][129] after K-loop
  float* part = sfi + 128 * 129;               // [2][3][128]

  const int tid = threadIdx.x;
  const int lane = tid & 63;
  const int w = tid >> 6;
  const int wr = w >> 1, wc = w & 1;
  const int b = blockIdx.y;
  const int colBase = blockIdx.x * 128;
  const int l15 = lane & 15, l4 = lane >> 4;
  f32x4 acc[4][4] = {};

  const bf16* bP[4];
  const bf16* gP[4];
  const bf16* hP[4];
#pragma unroll
  for (int i = 0; i < 4; ++i) {
    int c = tid + 256 * i;
    int r = c >> 3;
    int ql = (c & 7) ^ (r & 7);
    bP[i] = Wfit + (size_t)(colBase + r) * KFI + ql * 8;
    gP[i] = gcur + (size_t)b * H_ + ql * 8;
    hP[i] = hpad + ((size_t)(b * LP + r + 1)) * H_ + ql * 8;
  }

  auto step_ = [&](const bf16* const* ap, int ko, int kb) {
#pragma unroll
    for (int i = 0; i < 4; ++i) {
      gload16(ap[i] + ko, &As[(tid + 256 * i) * 8]);
      gload16(bP[i] + kb, &Bs[(tid + 256 * i) * 8]);
    }
    __syncthreads();
#pragma unroll
    for (int kh = 0; kh < 2; ++kh) {
      bf16x8 aF[4], bF[4];
#pragma unroll
      for (int m = 0; m < 4; ++m) {
        int row = wr * 64 + m * 16 + l15;
        aF[m] = *(const bf16x8*)&As[row * 64 +
                                    (((kh << 2) + l4) ^ (l15 & 7)) * 8];
      }
#pragma unroll
      for (int n = 0; n < 4; ++n) {
        int row = wc * 64 + n * 16 + l15;
        bF[n] = *(const bf16x8*)&Bs[row * 64 +
                                    (((kh << 2) + l4) ^ (l15 & 7)) * 8];
      }
#pragma unroll
      for (int m = 0; m < 4; ++m)
#pragma unroll
        for (int n = 0; n < 4; ++n)
          acc[m][n] = __builtin_amdgcn_mfma_f32_16x16x32_bf16(
              aF[m], bF[n], acc[m][n], 0, 0, 0);
    }
    __syncthreads();
  };

  for (int t = 0; t < 8; ++t) step_(gP, t * 64, t * 64);
  for (int t = 8; t < 16; ++t) step_(hP, (t - 8) * 64, t * 64);

  // fi tile -> LDS (staging buffers dead)
#pragma unroll
  for (int m = 0; m < 4; ++m) {
#pragma unroll
    for (int n = 0; n < 4; ++n) {
      int hl_ = wc * 64 + n * 16 + l15;
      float bv = bfi[colBase + hl_];
#pragma unroll
      for (int j = 0; j < 4; ++j) {
        int l = wr * 64 + m * 16 + l4 * 4 + j;
        sfi[hl_ * 129 + l] = acc[m][n][j] + bv;
      }
    }
  }
  __syncthreads();

  {
    int h = tid & 127, half = tid >> 7;
    int hcol = colBase + h;
    const float* mp = maskf + b * L_;
    float m = -3.0e38f, s = 0.f, tv = 0.f;
    for (int l = half * 64; l < half * 64 + 64; ++l) {
      if (mp[l] > 0.f) {
        float xv = sfi[h * 129 + l];
        float vv = c_new[((size_t)(b * L_ + l)) * H_ + hcol];
        float m2 = fmaxf(m, xv);
        float sc = expf(m - m2);
        float e = expf(xv - m2);
        s = s * sc + e;
        tv = tv * sc + e * vv;
        m = m2;
      }
    }
    part[half * 384 + h] = m;
    part[half * 384 + 128 + h] = s;
    part[half * 384 + 256 + h] = tv;
  }
  __syncthreads();
  if (tid < 128) {
    int hcol = colBase + tid;
    int i0 = b * H_ + hcol;
    float m0 = part[tid], s0 = part[128 + tid], t0 = part[256 + tid];
    float m1 = part[384 + tid], s1 = part[384 + 128 + tid],
          t1v = part[384 + 256 + tid];
    float mm = fmaxf(m0, m1);
    float e0 = expf(m0 - mm), e1 = expf(m1 - mm);
    float ss = s0 * e0 + s1 * e1;
    float tt = t0 * e0 + t1v * e1;
    float f = fg[i0];
    float m2 = fmaxf(mm, f);
    float ea = expf(mm - m2), eb = expf(f - m2);
    ss = ss * ea + eb;
    tt = tt * ea + cg_old[i0] * eb;
    float cgn = tt / ss;
    float gn = og[i0] * tanhf(cgn);
    cg_new[i0] = cgn;
    g_new[i0] = gn;
    gcur_new[i0] = __float2bfloat16(gn);
  }
}

// ---------------- fused cell update + h-mean ---------------------------------
// grid (H/64, B), 512 threads: 8 l-rows x 64 h-cols, 16 iterations over L.
__global__ __launch_bounds__(512) void cell_mean_kernel(
    const bf16* __restrict__ gates, const float* __restrict__ c_old,
    const float* __restrict__ cg_old, const float* __restrict__ maskf,
    const float* __restrict__ invlens, bf16* __restrict__ hpad,
    float* __restrict__ c_new, float* __restrict__ havg) {
  __shared__ float part[8][64];
  const int b = blockIdx.y;
  const int h0 = blockIdx.x * 64;
  const int hh = threadIdx.x & 63;
  const int lq = threadIdx.x >> 6;  // 0..7
  const int hcol = h0 + hh;
  const float cgv = cg_old[b * H_ + hcol];
  float s = 0.f;
  for (int i = 0; i < 16; ++i) {
    int l = i * 8 + lq;
    int bl = b * L_ + l;
    float gl_[7];
#pragma unroll
    for (int gt = 0; gt < 7; ++gt) {
      bf16 hv = gates[((size_t)(bl >> 2) * G7 + gt * H_ + hcol) * 4 + (bl & 3)];
      gl_[gt] = __bfloat162float(hv);
    }
    float m =
        fmaxf(fmaxf(fmaxf(gl_[0], gl_[1]), fmaxf(gl_[2], gl_[3])), gl_[4]);
    float ei = expf(gl_[0] - m), el = expf(gl_[1] - m), ef = expf(gl_[2] - m),
          er = expf(gl_[3] - m), es = expf(gl_[4] - m);
    float inv = 1.f / (ei + el + ef + er + es);
    float o = 1.f / (1.f + expf(-gl_[5]));
    float u = tanhf(gl_[6]);
    float cprev = (l >= 1) ? c_old[(size_t)(bl - 1) * H_ + hcol] : 0.f;
    float ccur = c_old[(size_t)bl * H_ + hcol];
    float cnext = (l < L_ - 1) ? c_old[(size_t)(bl + 1) * H_ + hcol] : 0.f;
    float mk = maskf[bl];
    float cn = (el * cprev + ef * ccur + er * cnext + es * cgv + ei * u) *
               inv * mk;
    float hn = o * tanhf(cn) * mk;
    c_new[(size_t)bl * H_ + hcol] = cn;
    hpad[((size_t)(b * LP + l + 1)) * H_ + hcol] = __float2bfloat16(hn);
    s += hn;
  }
  part[lq][hh] = s;
  __syncthreads();
  if (threadIdx.x < 64) {
    int t = threadIdx.x;
    float v = 0.f;
#pragma unroll
    for (int k = 0; k < 8; ++k) v += part[k][t];
    havg[b * H_ + h0 + t] = v * invlens[b];
  }
}

// deterministic parallel mean over L from bf16 hpad (init only)
__global__ __launch_bounds__(256) void reduce_mean_v2(
    const bf16* __restrict__ hpad, const float* __restrict__ invlens,
    float* __restrict__ outf, bf16* __restrict__ outb) {
  __shared__ float sm[4][64];
  int b = blockIdx.y, h0 = blockIdx.x * 64;
  int lg = threadIdx.x >> 6, hh = threadIdx.x & 63;
  float s = 0.f;
  for (int l = lg * 32; l < lg * 32 + 32; ++l)
    s += __bfloat162float(hpad[((size_t)(b * LP + l + 1)) * H_ + h0 + hh]);
  sm[lg][hh] = s;
  __syncthreads();
  if (threadIdx.x < 64) {
    int t = threadIdx.x;
    float m = (sm[0][t] + sm[1][t] + sm[2][t] + sm[3][t]) * invlens[b];
    outf[b * H_ + h0 + t] = m;
    if (outb) outb[b * H_ + h0 + t] = __float2bfloat16(m);
  }
}

// ---------------- batched vector GEMM (z-muxed two outputs) -----------------
__global__ __launch_bounds__(256) void batch_vec_gemm(
    const float* __restrict__ in1, int K1, const float* __restrict__ in2,
    int K2, const float* __restrict__ Wa, const float* __restrict__ ba,
    float* __restrict__ outa, int acta, const float* __restrict__ Wb,
    const float* __restrict__ bb, float* __restrict__ outb, int actb, int N) {
  const float* W = (blockIdx.z == 0) ? Wa : Wb;
  const float* bias = (blockIdx.z == 0) ? ba : bb;
  float* op = (blockIdx.z == 0) ? outa : outb;
  int act = (blockIdx.z == 0) ? acta : actb;
  __shared__ float vin[1024];
  __shared__ float red[4][64];
  const int K = K1 + K2;
  const int n0 = blockIdx.x * 64, b = blockIdx.y;
  for (int i = threadIdx.x; i < K; i += 256)
    vin[i] = (i < K1) ? in1[(size_t)b * K1 + i]
                      : in2[(size_t)b * K2 + (i - K1)];
  __syncthreads();
  const int o = threadIdx.x & 63, kp = threadIdx.x >> 6;
  float acc = 0.f;
  const int kc = K >> 2;
#pragma unroll 4
  for (int k = kp * kc; k < kp * kc + kc; ++k)
    acc = fmaf(vin[k], W[(size_t)k * N + n0 + o], acc);
  red[kp][o] = acc;
  __syncthreads();
  if (threadIdx.x < 64) {
    int t = threadIdx.x;
    float v = red[0][t] + red[1][t] + red[2][t] + red[3][t] + bias[n0 + t];
    if (act == 1) v = 1.f / (1.f + expf(-v));
    else if (act == 2) v = tanhf(v);
    op[(size_t)b * N + n0 + t] = v;
  }
}

// ---------------- fused final head: out = logsoftmax(tanh(g@W1+b1)@W2+b2) ---
__global__ __launch_bounds__(256) void final_head_kernel(
    const float* __restrict__ g, const float* __restrict__ W1,
    const float* __restrict__ b1, const float* __restrict__ W2,
    const float* __restrict__ b2, float* __restrict__ out) {
  __shared__ float gv[H_];
  __shared__ float t1s[2 * H_];
  __shared__ float red[256][6];
  const int b = blockIdx.x;
  const int tid = threadIdx.x;
  for (int i = tid; i < H_; i += 256) gv[i] = g[b * H_ + i];
  __syncthreads();
  float accp[4];
#pragma unroll
  for (int p = 0; p < 4; ++p) accp[p] = b1[tid + p * 256];
  for (int k = 0; k < H_; ++k) {
    float gk = gv[k];
#pragma unroll
    for (int p = 0; p < 4; ++p)
      accp[p] = fmaf(gk, W1[(size_t)k * (2 * H_) + tid + p * 256], accp[p]);
  }
#pragma unroll
  for (int p = 0; p < 4; ++p) t1s[tid + p * 256] = tanhf(accp[p]);
  __syncthreads();
  float pd[DOUT_] = {0.f, 0.f, 0.f, 0.f, 0.f};
#pragma unroll
  for (int p = 0; p < 4; ++p) {
    int j = tid + p * 256;
    float tv = t1s[j];
#pragma unroll
    for (int d = 0; d < DOUT_; ++d)
      pd[d] = fmaf(tv, W2[(size_t)j * DOUT_ + d], pd[d]);
  }
#pragma unroll
  for (int d = 0; d < DOUT_; ++d) red[tid][d] = pd[d];
  __syncthreads();
  for (int stride = 128; stride >= 1; stride >>= 1) {
    if (tid < stride) {
#pragma unroll
      for (int d = 0; d < DOUT_; ++d) red[tid][d] += red[tid + stride][d];
    }
    __syncthreads();
  }
  if (tid == 0) {
    float lg[DOUT_];
#pragma unroll
    for (int d = 0; d < DOUT_; ++d) lg[d] = red[0][d] + b2[d];
    float m = lg[0];
#pragma unroll
    for (int d = 1; d < DOUT_; ++d) m = fmaxf(m, lg[d]);
    float s = 0.f;
#pragma unroll
    for (int d = 0; d < DOUT_; ++d) s += expf(lg[d] - m);
    float ls = logf(s);
#pragma unroll
    for (int d = 0; d < DOUT_; ++d) out[b * DOUT_ + d] = lg[d] - m - ls;
  }
}

// ---------------- host ----------------
extern "C" void kernel_launch(void* const* d_in, const int* in_sizes, int n_in,
                              void* d_out, int out_size, void* d_ws,
                              size_t ws_size, hipStream_t stream) {
  (void)in_sizes; (void)n_in; (void)out_size; (void)ws_size;
  const int* tokens = (const int*)d_in[0];
  const int* lengths = (const int*)d_in[1];
  const float* embed = (const float*)d_in[2];
  const float* W0 = (const float*)d_in[3];
  const float* b0 = (const float*)d_in[4];
  const float* Wg = (const float*)d_in[5];
  const float* bg = (const float*)d_in[6];
  const float* Wgf = (const float*)d_in[7];
  const float* bgf = (const float*)d_in[8];
  const float* Wfi = (const float*)d_in[9];
  const float* bfi = (const float*)d_in[10];
  const float* Wgo = (const float*)d_in[11];
  const float* bgo = (const float*)d_in[12];
  const float* W1 = (const float*)d_in[13];
  const float* b1 = (const float*)d_in[14];
  const float* W2 = (const float*)d_in[15];
  const float* b2 = (const float*)d_in[16];
  float* out = (float*)d_out;

  float* ws = (float*)d_ws;
  size_t off = 0;
  auto alloc = [&](size_t nf) {
    float* p = ws + off;
    off += (nf + 7) & ~(size_t)7;
    return p;
  };
  bf16* xb = (bf16*)alloc((size_t)B_ * L_ * EP / 2);       // [4096][320]
  float* maskf = alloc(B_ * L_);
  float* invlens = alloc(B_);
  bf16* hpad = (bf16*)alloc((size_t)B_ * LP * H_ / 2);     // [32][130][512]
  float* cb0 = alloc((size_t)B_ * L_ * H_);
  float* cb1 = alloc((size_t)B_ * L_ * H_);
  float* g = alloc(B_ * H_);
  bf16* gcurA = (bf16*)alloc(B_ * H_ / 2);
  bf16* gcurB = (bf16*)alloc(B_ * H_ / 2);
  float* cgb0 = alloc(B_ * H_);
  float* cgb1 = alloc(B_ * H_);
  float* havg = alloc(B_ * H_);
  float* fg = alloc(B_ * H_);
  float* og = alloc(B_ * H_);
  bf16* gatesb = (bf16*)alloc((size_t)B_ * L_ * G7 / 2);   // perm layout
  bf16* Wgt = (bf16*)alloc((size_t)G7 * KGATES / 2);       // [3584][2368]
  bf16* W0t = (bf16*)alloc((size_t)H_ * EP / 2);           // [512][320]
  bf16* Wfit = (bf16*)alloc((size_t)H_ * KFI / 2);         // [512][1024]

  // ---- init ----
  mask_lens_kernel<<<(B_ * L_ + 255) / 256, 256, 0, stream>>>(lengths, maskf,
                                                              invlens);
  embed_bf16_kernel<<<(B_ * L_ * EP + 255) / 256, 256, 0, stream>>>(tokens,
                                                                    embed, xb);
  // Wgt: cols [0,1536)=Wg rows[0,1536); [1536,2048)=rows[1836,2348);
  //      [2048,2368)=rows[1536,1836) zero-padded
  transpose_to_bf16<<<dim3(24, G7 / 64), 256, 0, stream>>>(Wg, Wgt, 1536, G7,
                                                           KGATES);
  transpose_to_bf16<<<dim3(8, G7 / 64), 256, 0, stream>>>(
      Wg + (size_t)1836 * G7, Wgt + 1536, 512, G7, KGATES);
  transpose_to_bf16<<<dim3(5, G7 / 64), 256, 0, stream>>>(
      Wg + (size_t)1536 * G7, Wgt + 2048, 300, G7, KGATES);
  transpose_to_bf16<<<dim3(5, H_ / 64), 256, 0, stream>>>(W0, W0t, 300, H_, EP);
  transpose_to_bf16<<<dim3(16, H_ / 64), 256, 0, stream>>>(Wfi, Wfit, 1024, H_,
                                                           KFI);
  fill_pad<<<(B_ * 2 * H_ + 255) / 256, 256, 0, stream>>>(hpad);
  // h0 = tanh(xb @ W0 + b0) * mask -> hpad
  gemm_mfma<0, 3><<<dim3(H_ / 128, (B_ * L_) / 128), 256, 0, stream>>>(
      xb, nullptr, nullptr, W0t, b0, maskf, hpad, H_, EP, 1);
  reduce_mean_v2<<<dim3(8, B_), 256, 0, stream>>>(hpad, invlens, g, gcurA);
  fill_zero<<<(B_ * L_ * H_ + 255) / 256, 256, 0, stream>>>(cb0, B_ * L_ * H_);
  fill_zero<<<(B_ * H_ + 255) / 256, 256, 0, stream>>>(cgb0, B_ * H_);

  float* cb[2] = {cb0, cb1};
  float* cgb[2] = {cgb0, cgb1};
  bf16* gc[2] = {gcurA, gcurB};
  int cur = 0;
  for (int step = 0; step < NSTEP; ++step) {
    int nxt = cur ^ 1;
    // gates = [hl|h|hr|g|x] @ Wgt^T + bg   (perm bf16 out)
    gemm_mfma<2, 5><<<dim3(G7 / 128, (B_ * L_) / 128), 256, 0, stream>>>(
        hpad, gc[cur], xb, Wgt, bg, nullptr, gatesb, G7, KGATES, 0);
    cell_mean_kernel<<<dim3(H_ / 64, B_), 512, 0, stream>>>(
        gatesb, cb[cur], cgb[cur], maskf, invlens, hpad, cb[nxt], havg);
    batch_vec_gemm<<<dim3(8, B_, 2), 256, 0, stream>>>(
        g, H_, havg, H_, Wgf, bgf, fg, 0, Wgo, bgo, og, 1, H_);
    fi_slot_kernel<<<dim3(H_ / 128, B_), 256, 0, stream>>>(
        gc[cur], hpad, Wfit, bfi, fg, og, cb[nxt], cgb[cur], maskf, cgb[nxt],
        g, gc[nxt]);
    cur = nxt;
  }
  final_head_kernel<<<B_, 256, 0, stream>>>(g, W1, b1, W2, b2, out);
}

// Round 11
// 822.960 us; speedup vs baseline: 1.1391x; 1.1391x over previous
//
#include <hip/hip_runtime.h>
#include <hip/hip_bf16.h>
#include <math.h>

#define B_ 32
#define L_ 128
#define LP 130      // padded L (zero row before/after each batch)
#define E_ 300
#define EP 320      // padded E (%64)
#define H_ 512
#define DOUT_ 5
#define NSTEP 5
#define G7 3584     // 7H
#define KGATES 1856 // 1536 (hl|h|hr from hpad) + 320 (x padded)
#define KFI 512     // h only (g handled via gfi per-batch bias)

typedef __hip_bfloat16 bf16;
using bf16x8 = __attribute__((ext_vector_type(8))) __bf16;
using f32x4 = __attribute__((ext_vector_type(4))) float;

__device__ __forceinline__ void gload16(const void* g, void* l) {
  __builtin_amdgcn_global_load_lds(
      (const __attribute__((address_space(1))) void*)g,
      (__attribute__((address_space(3))) void*)l, 16, 0, 0);
}

// ---------------- small helpers ----------------
__global__ void fill_zero(float* __restrict__ p, int n) {
  int i = blockIdx.x * blockDim.x + threadIdx.x;
  if (i < n) p[i] = 0.f;
}

__global__ void mask_lens_kernel(const int* __restrict__ lengths,
                                 float* __restrict__ maskf,
                                 float* __restrict__ invlens) {
  int i = blockIdx.x * blockDim.x + threadIdx.x;
  if (i < B_ * L_) {
    int b = i >> 7, l = i & 127;
    maskf[i] = (l < lengths[b]) ? 1.f : 0.f;
    if (l == 0) invlens[b] = 1.f / fmaxf((float)lengths[b], 1.f);
  }
}

__global__ void embed_bf16_kernel(const int* __restrict__ tokens,
                                  const float* __restrict__ embed,
                                  bf16* __restrict__ xb) {
  int i = blockIdx.x * blockDim.x + threadIdx.x;  // B*L*EP
  if (i >= B_ * L_ * EP) return;
  int e = i % EP, bl = i / EP;
  float v = (e < E_) ? embed[(size_t)tokens[bl] * E_ + e] : 0.f;
  xb[i] = __float2bfloat16(v);
}

__global__ void fill_pad(bf16* __restrict__ hpad) {
  int i = blockIdx.x * blockDim.x + threadIdx.x;  // B*2*H
  if (i >= B_ * 2 * H_) return;
  int hh = i & (H_ - 1);
  int r = (i >> 9) & 1, b = i >> 10;
  hpad[((size_t)(b * LP + r * (LP - 1))) * H_ + hh] = __float2bfloat16(0.f);
}

// transpose + cast: Wt[n][k] = W[k][n]; grid (Kregion/64, Ncols/64).
__global__ __launch_bounds__(256) void transpose_to_bf16(
    const float* __restrict__ W, bf16* __restrict__ Wt, int Kreal, int Ncols,
    int dstStride) {
  __shared__ float tile[64][65];
  const int k0 = blockIdx.x * 64, n0 = blockIdx.y * 64;
  const int t = threadIdx.x;
  const int nn = t & 63, kk0 = t >> 6;
#pragma unroll
  for (int p = 0; p < 16; ++p) {
    int kk = kk0 + p * 4;
    int gk = k0 + kk;
    tile[kk][nn] = (gk < Kreal) ? W[(size_t)gk * Ncols + n0 + nn] : 0.f;
  }
  __syncthreads();
#pragma unroll
  for (int p = 0; p < 2; ++p) {
    int r = (t >> 3) + p * 32;
    int kb = (t & 7) * 8;
    union { ushort h[8]; uint4 v; } u;
#pragma unroll
    for (int e = 0; e < 8; ++e) {
      bf16 b = __float2bfloat16(tile[kb + e][r]);
      u.h[e] = *(ushort*)&b;
    }
    *(uint4*)&Wt[(size_t)(n0 + r) * dstStride + k0 + kb] = u.v;
  }
}

// ---------------- bf16 MFMA GEMM, 128x128 tile, BK=64 ------------------------
// AMAP 0: A linear [M][KP].
// AMAP 2: gates A: k<1536 hpad rows (b*130+l ..+2); [1536,1856) X3[row].
// OUTMODE 3: bf16 into hpad (+1 row), act/rowscale.
// OUTMODE 5: bf16 fragment-permuted (idx = ((row>>2)*N+col)*4 + (row&3)),
//            + optional per-batch fp32 bias b2batch[batch][N].
template <int AMAP, int OUTMODE>
__global__ __launch_bounds__(256) void gemm_mfma(
    const bf16* __restrict__ A, const bf16* __restrict__ X3,
    const bf16* __restrict__ Bt, const float* __restrict__ bias,
    const float* __restrict__ b2batch, const float* __restrict__ rowscale,
    void* __restrict__ Cout, int N, int KP, int act) {
  __shared__ ushort As[128 * 64];
  __shared__ ushort Bs[128 * 64];
  const int tid = threadIdx.x;
  const int lane = tid & 63;
  const int w = tid >> 6;
  const int wr = w >> 1, wc = w & 1;
  // XCD-aware bijective block swizzle (grids %8==0)
  const int nbx = gridDim.x;
  const int nwg = nbx * gridDim.y;
  int id = blockIdx.y * nbx + blockIdx.x;
  if ((nwg & 7) == 0) { int q = nwg >> 3; id = (id & 7) * q + (id >> 3); }
  const int bxi = id % nbx, byi = id / nbx;
  const int rowBase = byi * 128, colBase = bxi * 128;
  const int l15 = lane & 15, l4 = lane >> 4;
  f32x4 acc[4][4] = {};

  const bf16* bP[4];
  const bf16* aP[4];
  const bf16* xP[4];
#pragma unroll
  for (int i = 0; i < 4; ++i) {
    int c = tid + 256 * i;
    int r = c >> 3;
    int ql = (c & 7) ^ (r & 7);  // inverse-swizzled logical chunk
    bP[i] = Bt + (size_t)(colBase + r) * KP + ql * 8;
    if constexpr (AMAP == 0) {
      aP[i] = A + (size_t)(rowBase + r) * KP + ql * 8;
    } else {
      const int b = rowBase >> 7;  // BM=128 == L: one batch per block row
      aP[i] = A + ((size_t)(b * LP + r)) * H_ + ql * 8;   // hpad region
      xP[i] = X3 + (size_t)(rowBase + r) * EP + ql * 8;   // x region
    }
  }

  auto step_ = [&](const bf16* const* ap, int ko, int kb) {
#pragma unroll
    for (int i = 0; i < 4; ++i) {
      gload16(ap[i] + ko, &As[(tid + 256 * i) * 8]);
      gload16(bP[i] + kb, &Bs[(tid + 256 * i) * 8]);
    }
    __syncthreads();
#pragma unroll
    for (int kh = 0; kh < 2; ++kh) {
      bf16x8 aF[4], bF[4];
#pragma unroll
      for (int m = 0; m < 4; ++m) {
        int row = wr * 64 + m * 16 + l15;
        aF[m] = *(const bf16x8*)&As[row * 64 +
                                    (((kh << 2) + l4) ^ (l15 & 7)) * 8];
      }
#pragma unroll
      for (int n = 0; n < 4; ++n) {
        int row = wc * 64 + n * 16 + l15;
        bF[n] = *(const bf16x8*)&Bs[row * 64 +
                                    (((kh << 2) + l4) ^ (l15 & 7)) * 8];
      }
#pragma unroll
      for (int m = 0; m < 4; ++m)
#pragma unroll
        for (int n = 0; n < 4; ++n)
          acc[m][n] = __builtin_amdgcn_mfma_f32_16x16x32_bf16(
              aF[m], bF[n], acc[m][n], 0, 0, 0);
    }
    __syncthreads();
  };

  if constexpr (AMAP == 0) {
    const int nIter = KP >> 6;
    for (int t = 0; t < nIter; ++t) step_(aP, t * 64, t * 64);
  } else {
    for (int t = 0; t < 24; ++t) step_(aP, t * 64, t * 64);
    for (int t = 24; t < 29; ++t) step_(xP, (t - 24) * 64, t * 64);
  }

  const int bidx = rowBase >> 7;
#pragma unroll
  for (int m = 0; m < 4; ++m) {
#pragma unroll
    for (int n = 0; n < 4; ++n) {
      int col = colBase + wc * 64 + n * 16 + l15;
      float bv = bias[col];
      if (b2batch) bv += b2batch[(size_t)bidx * N + col];
      if constexpr (OUTMODE == 5) {
        bf16 tmp[4];
#pragma unroll
        for (int j = 0; j < 4; ++j)
          tmp[j] = __float2bfloat16(acc[m][n][j] + bv);
        int row0 = rowBase + wr * 64 + m * 16 + l4 * 4;
        *(uint2*)&((bf16*)Cout)[((size_t)(row0 >> 2) * N + col) * 4] =
            *(uint2*)tmp;
      } else {  // OUTMODE == 3
#pragma unroll
        for (int j = 0; j < 4; ++j) {
          int row = rowBase + wr * 64 + m * 16 + l4 * 4 + j;
          float v = acc[m][n][j] + bv;
          if (act == 1) v = tanhf(v);
          v *= rowscale[row];
          size_t oi = ((size_t)((row >> 7) * LP + (row & 127) + 1)) * H_ + col;
          ((bf16*)Cout)[oi] = __float2bfloat16(v);
        }
      }
    }
  }
}

// ---------------- per-batch g-vector GEMMs: gg = g@Wg_g, gfi = g@Wfi_top ----
// grid (64, B): bx<56 -> gg slice (N=3584); bx>=56 -> gfi slice (N=512).
__global__ __launch_bounds__(256) void gvec_gemm(
    const float* __restrict__ g, const float* __restrict__ Wgg,
    const float* __restrict__ Wfi, float* __restrict__ gg,
    float* __restrict__ gfi) {
  __shared__ float vin[H_];
  __shared__ float red[4][64];
  const int b = blockIdx.y;
  for (int i = threadIdx.x; i < H_; i += 256) vin[i] = g[(size_t)b * H_ + i];
  __syncthreads();
  const int o = threadIdx.x & 63, kp = threadIdx.x >> 6;
  const bool isg = blockIdx.x < 56;
  const int n0 = isg ? blockIdx.x * 64 : (blockIdx.x - 56) * 64;
  const float* W = isg ? Wgg : Wfi;
  const int ldw = isg ? G7 : H_;
  float acc = 0.f;
#pragma unroll 4
  for (int k = kp * 128; k < kp * 128 + 128; ++k)
    acc = fmaf(vin[k], W[(size_t)k * ldw + n0 + o], acc);
  red[kp][o] = acc;
  __syncthreads();
  if (threadIdx.x < 64) {
    int t = threadIdx.x;
    float v = red[0][t] + red[1][t] + red[2][t] + red[3][t];
    if (isg) gg[(size_t)b * G7 + n0 + t] = v;
    else gfi[(size_t)b * H_ + n0 + t] = v;
  }
}

// ---------------- fused fi GEMM (K=512) + slot softmax, 64-col tiles --------
__global__ __launch_bounds__(256) void fi_slot_kernel(
    const bf16* __restrict__ hpad, const bf16* __restrict__ Wfit,
    const float* __restrict__ bfi, const float* __restrict__ gfi,
    const float* __restrict__ fg, const float* __restrict__ og,
    const float* __restrict__ c_new, const float* __restrict__ cg_old,
    const float* __restrict__ maskf, float* __restrict__ cg_new,
    float* __restrict__ g_new) {
  __shared__ __align__(16) char smem[64 * 129 * 4 + 3072];  // 36096 B
  ushort* As = (ushort*)smem;              // [128*64] staging (dead later)
  ushort* Bs = As + 128 * 64;              // [64*64]
  float* sfi = (float*)smem;               // [64 cols][129] after K-loop
  float* part = sfi + 64 * 129;            // [4][3][64]

  const int tid = threadIdx.x;
  const int lane = tid & 63;
  const int w = tid >> 6;                  // wave -> rows w*32..w*32+31
  const int b = blockIdx.y;
  const int colBase = blockIdx.x * 64;
  const int l15 = lane & 15, l4 = lane >> 4;
  f32x4 acc[2][4] = {};

  const bf16* aP[4];
  const bf16* bP[2];
#pragma unroll
  for (int i = 0; i < 4; ++i) {
    int c = tid + 256 * i;
    int r = c >> 3;
    int ql = (c & 7) ^ (r & 7);
    aP[i] = hpad + ((size_t)(b * LP + r + 1)) * H_ + ql * 8;
  }
#pragma unroll
  for (int i = 0; i < 2; ++i) {
    int c = tid + 256 * i;
    int r = c >> 3;
    int ql = (c & 7) ^ (r & 7);
    bP[i] = Wfit + (size_t)(colBase + r) * KFI + ql * 8;
  }

  for (int t = 0; t < 8; ++t) {
    int k0 = t * 64;
#pragma unroll
    for (int i = 0; i < 4; ++i)
      gload16(aP[i] + k0, &As[(tid + 256 * i) * 8]);
#pragma unroll
    for (int i = 0; i < 2; ++i)
      gload16(bP[i] + k0, &Bs[(tid + 256 * i) * 8]);
    __syncthreads();
#pragma unroll
    for (int kh = 0; kh < 2; ++kh) {
      bf16x8 aF[2], bF[4];
#pragma unroll
      for (int m = 0; m < 2; ++m) {
        int row = w * 32 + m * 16 + l15;
        aF[m] = *(const bf16x8*)&As[row * 64 +
                                    (((kh << 2) + l4) ^ (l15 & 7)) * 8];
      }
#pragma unroll
      for (int n = 0; n < 4; ++n) {
        int row = n * 16 + l15;
        bF[n] = *(const bf16x8*)&Bs[row * 64 +
                                    (((kh << 2) + l4) ^ (l15 & 7)) * 8];
      }
#pragma unroll
      for (int m = 0; m < 2; ++m)
#pragma unroll
        for (int n = 0; n < 4; ++n)
          acc[m][n] = __builtin_amdgcn_mfma_f32_16x16x32_bf16(
              aF[m], bF[n], acc[m][n], 0, 0, 0);
    }
    __syncthreads();
  }

  // fi tile -> LDS
#pragma unroll
  for (int m = 0; m < 2; ++m) {
#pragma unroll
    for (int n = 0; n < 4; ++n) {
      int hl_ = n * 16 + l15;
      float bv = bfi[colBase + hl_] + gfi[(size_t)b * H_ + colBase + hl_];
#pragma unroll
      for (int j = 0; j < 4; ++j) {
        int l = w * 32 + m * 16 + l4 * 4 + j;
        sfi[hl_ * 129 + l] = acc[m][n][j] + bv;
      }
    }
  }
  __syncthreads();

  // online softmax over slots: 4 threads per column, 32 l each
  {
    int h = tid & 63, q = tid >> 6;
    int hcol = colBase + h;
    const float* mp = maskf + b * L_;
    float m = -3.0e38f, s = 0.f, tv = 0.f;
    for (int l = q * 32; l < q * 32 + 32; ++l) {
      if (mp[l] > 0.f) {
        float xv = sfi[h * 129 + l];
        float vv = c_new[((size_t)(b * L_ + l)) * H_ + hcol];
        float m2 = fmaxf(m, xv);
        float sc = expf(m - m2);
        float e = expf(xv - m2);
        s = s * sc + e;
        tv = tv * sc + e * vv;
        m = m2;
      }
    }
    part[q * 192 + h] = m;
    part[q * 192 + 64 + h] = s;
    part[q * 192 + 128 + h] = tv;
  }
  __syncthreads();
  if (tid < 64) {
    int hcol = colBase + tid;
    int i0 = b * H_ + hcol;
    float mm = part[tid], s0 = part[64 + tid], t0 = part[128 + tid];
#pragma unroll
    for (int k = 1; k < 4; ++k) {
      float mk = part[k * 192 + tid];
      float m2 = fmaxf(mm, mk);
      float e1 = expf(mm - m2), e2 = expf(mk - m2);
      s0 = s0 * e1 + part[k * 192 + 64 + tid] * e2;
      t0 = t0 * e1 + part[k * 192 + 128 + tid] * e2;
      mm = m2;
    }
    float f = fg[i0];
    float m2 = fmaxf(mm, f);
    float ea = expf(mm - m2), eb = expf(f - m2);
    s0 = s0 * ea + eb;
    t0 = t0 * ea + cg_old[i0] * eb;
    float cgn = t0 / s0;
    float gn = og[i0] * tanhf(cgn);
    cg_new[i0] = cgn;
    g_new[i0] = gn;
  }
}

// ---------------- fused cell update + h-mean (uint2-coalesced) --------------
// grid (H/64, B), 512 threads: lq=tid>>6 handles 4 groups of 4 consecutive l.
__global__ __launch_bounds__(512) void cell_mean_kernel(
    const bf16* __restrict__ gates, const float* __restrict__ c_old,
    const float* __restrict__ cg_old, const float* __restrict__ maskf,
    const float* __restrict__ invlens, bf16* __restrict__ hpad,
    float* __restrict__ c_new, float* __restrict__ havg) {
  __shared__ float part[8][64];
  const int b = blockIdx.y;
  const int h0 = blockIdx.x * 64;
  const int hh = threadIdx.x & 63;
  const int lq = threadIdx.x >> 6;  // 0..7
  const int hcol = h0 + hh;
  const float cgv = cg_old[b * H_ + hcol];
  float s = 0.f;
  for (int it = 0; it < 4; ++it) {
    const int gi = it * 8 + lq;     // 4-row group 0..31
    const int l0 = gi * 4;
    const size_t gbase = ((size_t)(b * 32 + gi) * G7 + hcol) * 4;
    uint2 gv[7];
#pragma unroll
    for (int gt = 0; gt < 7; ++gt)
      gv[gt] = *(const uint2*)&gates[gbase + (size_t)gt * H_ * 4];
    float crow[6];
#pragma unroll
    for (int jj = 0; jj < 6; ++jj) {
      int l = l0 + jj - 1;
      crow[jj] = (l >= 0 && l < L_)
                     ? c_old[((size_t)(b * L_ + l)) * H_ + hcol]
                     : 0.f;
    }
#pragma unroll
    for (int j = 0; j < 4; ++j) {
      int l = l0 + j;
      int bl = b * L_ + l;
      float gl_[7];
#pragma unroll
      for (int gt = 0; gt < 7; ++gt) {
        ushort us = ((const ushort*)&gv[gt])[j];
        bf16 hb;
        *(ushort*)&hb = us;
        gl_[gt] = __bfloat162float(hb);
      }
      float m = fmaxf(fmaxf(fmaxf(gl_[0], gl_[1]), fmaxf(gl_[2], gl_[3])),
                      gl_[4]);
      float ei = expf(gl_[0] - m), el = expf(gl_[1] - m),
            ef = expf(gl_[2] - m), er = expf(gl_[3] - m),
            es = expf(gl_[4] - m);
      float inv = 1.f / (ei + el + ef + er + es);
      float o = 1.f / (1.f + expf(-gl_[5]));
      float u = tanhf(gl_[6]);
      float mk = maskf[bl];
      float cn = (el * crow[j] + ef * crow[j + 1] + er * crow[j + 2] +
                  es * cgv + ei * u) * inv * mk;
      float hn = o * tanhf(cn) * mk;
      c_new[(size_t)bl * H_ + hcol] = cn;
      hpad[((size_t)(b * LP + l + 1)) * H_ + hcol] = __float2bfloat16(hn);
      s += hn;
    }
  }
  part[lq][hh] = s;
  __syncthreads();
  if (threadIdx.x < 64) {
    int t = threadIdx.x;
    float v = 0.f;
#pragma unroll
    for (int k = 0; k < 8; ++k) v += part[k][t];
    havg[b * H_ + h0 + t] = v * invlens[b];
  }
}

// deterministic parallel mean over L from bf16 hpad (init only)
__global__ __launch_bounds__(256) void reduce_mean_v2(
    const bf16* __restrict__ hpad, const float* __restrict__ invlens,
    float* __restrict__ outf) {
  __shared__ float sm[4][64];
  int b = blockIdx.y, h0 = blockIdx.x * 64;
  int lg = threadIdx.x >> 6, hh = threadIdx.x & 63;
  float s = 0.f;
  for (int l = lg * 32; l < lg * 32 + 32; ++l)
    s += __bfloat162float(hpad[((size_t)(b * LP + l + 1)) * H_ + h0 + hh]);
  sm[lg][hh] = s;
  __syncthreads();
  if (threadIdx.x < 64) {
    int t = threadIdx.x;
    outf[b * H_ + h0 + t] =
        (sm[0][t] + sm[1][t] + sm[2][t] + sm[3][t]) * invlens[b];
  }
}

// ---------------- batched vector GEMM (z-muxed two outputs) -----------------
__global__ __launch_bounds__(256) void batch_vec_gemm(
    const float* __restrict__ in1, int K1, const float* __restrict__ in2,
    int K2, const float* __restrict__ Wa, const float* __restrict__ ba,
    float* __restrict__ outa, int acta, const float* __restrict__ Wb,
    const float* __restrict__ bb, float* __restrict__ outb, int actb, int N) {
  const float* W = (blockIdx.z == 0) ? Wa : Wb;
  const float* bias = (blockIdx.z == 0) ? ba : bb;
  float* op = (blockIdx.z == 0) ? outa : outb;
  int act = (blockIdx.z == 0) ? acta : actb;
  __shared__ float vin[1024];
  __shared__ float red[4][64];
  const int K = K1 + K2;
  const int n0 = blockIdx.x * 64, b = blockIdx.y;
  for (int i = threadIdx.x; i < K; i += 256)
    vin[i] = (i < K1) ? in1[(size_t)b * K1 + i]
                      : in2[(size_t)b * K2 + (i - K1)];
  __syncthreads();
  const int o = threadIdx.x & 63, kp = threadIdx.x >> 6;
  float acc = 0.f;
  const int kc = K >> 2;
#pragma unroll 4
  for (int k = kp * kc; k < kp * kc + kc; ++k)
    acc = fmaf(vin[k], W[(size_t)k * N + n0 + o], acc);
  red[kp][o] = acc;
  __syncthreads();
  if (threadIdx.x < 64) {
    int t = threadIdx.x;
    float v = red[0][t] + red[1][t] + red[2][t] + red[3][t] + bias[n0 + t];
    if (act == 1) v = 1.f / (1.f + expf(-v));
    else if (act == 2) v = tanhf(v);
    op[(size_t)b * N + n0 + t] = v;
  }
}

// ---------------- fused final head -------------------------------------------
__global__ __launch_bounds__(256) void final_head_kernel(
    const float* __restrict__ g, const float* __restrict__ W1,
    const float* __restrict__ b1, const float* __restrict__ W2,
    const float* __restrict__ b2, float* __restrict__ out) {
  __shared__ float gv[H_];
  __shared__ float t1s[2 * H_];
  __shared__ float red[256][6];
  const int b = blockIdx.x;
  const int tid = threadIdx.x;
  for (int i = tid; i < H_; i += 256) gv[i] = g[b * H_ + i];
  __syncthreads();
  float accp[4];
#pragma unroll
  for (int p = 0; p < 4; ++p) accp[p] = b1[tid + p * 256];
  for (int k = 0; k < H_; ++k) {
    float gk = gv[k];
#pragma unroll
    for (int p = 0; p < 4; ++p)
      accp[p] = fmaf(gk, W1[(size_t)k * (2 * H_) + tid + p * 256], accp[p]);
  }
#pragma unroll
  for (int p = 0; p < 4; ++p) t1s[tid + p * 256] = tanhf(accp[p]);
  __syncthreads();
  float pd[DOUT_] = {0.f, 0.f, 0.f, 0.f, 0.f};
#pragma unroll
  for (int p = 0; p < 4; ++p) {
    int j = tid + p * 256;
    float tv = t1s[j];
#pragma unroll
    for (int d = 0; d < DOUT_; ++d)
      pd[d] = fmaf(tv, W2[(size_t)j * DOUT_ + d], pd[d]);
  }
#pragma unroll
  for (int d = 0; d < DOUT_; ++d) red[tid][d] = pd[d];
  __syncthreads();
  for (int stride = 128; stride >= 1; stride >>= 1) {
    if (tid < stride) {
#pragma unroll
      for (int d = 0; d < DOUT_; ++d) red[tid][d] += red[tid + stride][d];
    }
    __syncthreads();
  }
  if (tid == 0) {
    float lg[DOUT_];
#pragma unroll
    for (int d = 0; d < DOUT_; ++d) lg[d] = red[0][d] + b2[d];
    float m = lg[0];
#pragma unroll
    for (int d = 1; d < DOUT_; ++d) m = fmaxf(m, lg[d]);
    float s = 0.f;
#pragma unroll
    for (int d = 0; d < DOUT_; ++d) s += expf(lg[d] - m);
    float ls = logf(s);
#pragma unroll
    for (int d = 0; d < DOUT_; ++d) out[b * DOUT_ + d] = lg[d] - m - ls;
  }
}

// ---------------- host ----------------
extern "C" void kernel_launch(void* const* d_in, const int* in_sizes, int n_in,
                              void* d_out, int out_size, void* d_ws,
                              size_t ws_size, hipStream_t stream) {
  (void)in_sizes; (void)n_in; (void)out_size; (void)ws_size;
  const int* tokens = (const int*)d_in[0];
  const int* lengths = (const int*)d_in[1];
  const float* embed = (const float*)d_in[2];
  const float* W0 = (const float*)d_in[3];
  const float* b0 = (const float*)d_in[4];
  const float* Wg = (const float*)d_in[5];
  const float* bg = (const float*)d_in[6];
  const float* Wgf = (const float*)d_in[7];
  const float* bgf = (const float*)d_in[8];
  const float* Wfi = (const float*)d_in[9];
  const float* bfi = (const float*)d_in[10];
  const float* Wgo = (const float*)d_in[11];
  const float* bgo = (const float*)d_in[12];
  const float* W1 = (const float*)d_in[13];
  const float* b1 = (const float*)d_in[14];
  const float* W2 = (const float*)d_in[15];
  const float* b2 = (const float*)d_in[16];
  float* out = (float*)d_out;

  float* ws = (float*)d_ws;
  size_t off = 0;
  auto alloc = [&](size_t nf) {
    float* p = ws + off;
    off += (nf + 7) & ~(size_t)7;
    return p;
  };
  bf16* xb = (bf16*)alloc((size_t)B_ * L_ * EP / 2);       // [4096][320]
  float* maskf = alloc(B_ * L_);
  float* invlens = alloc(B_);
  bf16* hpad = (bf16*)alloc((size_t)B_ * LP * H_ / 2);     // [32][130][512]
  float* cb0 = alloc((size_t)B_ * L_ * H_);
  float* cb1 = alloc((size_t)B_ * L_ * H_);
  float* g = alloc(B_ * H_);
  float* cgb0 = alloc(B_ * H_);
  float* cgb1 = alloc(B_ * H_);
  float* havg = alloc(B_ * H_);
  float* fg = alloc(B_ * H_);
  float* og = alloc(B_ * H_);
  float* gg = alloc((size_t)B_ * G7);                      // [32][3584]
  float* gfi = alloc(B_ * H_);                             // [32][512]
  bf16* gatesb = (bf16*)alloc((size_t)B_ * L_ * G7 / 2);   // perm layout
  bf16* Wgt = (bf16*)alloc((size_t)G7 * KGATES / 2);       // [3584][1856]
  bf16* W0t = (bf16*)alloc((size_t)H_ * EP / 2);           // [512][320]
  bf16* Wfit = (bf16*)alloc((size_t)H_ * KFI / 2);         // [512][512]

  // ---- init ----
  mask_lens_kernel<<<(B_ * L_ + 255) / 256, 256, 0, stream>>>(lengths, maskf,
                                                              invlens);
  embed_bf16_kernel<<<(B_ * L_ * EP + 255) / 256, 256, 0, stream>>>(tokens,
                                                                    embed, xb);
  // Wgt cols: [0,1536)=Wg rows[0,1536) (hl|h|hr); [1536,1856)=rows[1536,1836)
  // (x region, zero-padded to 320). g rows [1836,2348) stay fp32 for gvec.
  transpose_to_bf16<<<dim3(24, G7 / 64), 256, 0, stream>>>(Wg, Wgt, 1536, G7,
                                                           KGATES);
  transpose_to_bf16<<<dim3(5, G7 / 64), 256, 0, stream>>>(
      Wg + (size_t)1536 * G7, Wgt + 1536, 300, G7, KGATES);
  transpose_to_bf16<<<dim3(5, H_ / 64), 256, 0, stream>>>(W0, W0t, 300, H_, EP);
  transpose_to_bf16<<<dim3(8, H_ / 64), 256, 0, stream>>>(
      Wfi + (size_t)H_ * H_, Wfit, H_, H_, KFI);  // bottom 512 rows (h part)
  fill_pad<<<(B_ * 2 * H_ + 255) / 256, 256, 0, stream>>>(hpad);
  // h0 = tanh(xb @ W0 + b0) * mask -> hpad
  gemm_mfma<0, 3><<<dim3(H_ / 128, (B_ * L_) / 128), 256, 0, stream>>>(
      xb, nullptr, W0t, b0, nullptr, maskf, hpad, H_, EP, 1);
  reduce_mean_v2<<<dim3(8, B_), 256, 0, stream>>>(hpad, invlens, g);
  fill_zero<<<(B_ * L_ * H_ + 255) / 256, 256, 0, stream>>>(cb0, B_ * L_ * H_);
  fill_zero<<<(B_ * H_ + 255) / 256, 256, 0, stream>>>(cgb0, B_ * H_);

  float* cb[2] = {cb0, cb1};
  float* cgb[2] = {cgb0, cgb1};
  int cur = 0;
  for (int step = 0; step < NSTEP; ++step) {
    int nxt = cur ^ 1;
    // per-batch g contributions (gg for gates, gfi for fi)
    gvec_gemm<<<dim3(64, B_), 256, 0, stream>>>(g, Wg + (size_t)1836 * G7,
                                                Wfi, gg, gfi);
    // gates = [hl|h|hr|x] @ Wgt^T + bg + gg[b]   (perm bf16 out)
    gemm_mfma<2, 5><<<dim3(G7 / 128, (B_ * L_) / 128), 256, 0, stream>>>(
        hpad, xb, Wgt, bg, gg, nullptr, gatesb, G7, KGATES, 0);
    cell_mean_kernel<<<dim3(H_ / 64, B_), 512, 0, stream>>>(
        gatesb, cb[cur], cgb[cur], maskf, invlens, hpad, cb[nxt], havg);
    batch_vec_gemm<<<dim3(8, B_, 2), 256, 0, stream>>>(
        g, H_, havg, H_, Wgf, bgf, fg, 0, Wgo, bgo, og, 1, H_);
    fi_slot_kernel<<<dim3(H_ / 64, B_), 256, 0, stream>>>(
        hpad, Wfit, bfi, gfi, fg, og, cb[nxt], cgb[cur], maskf, cgb[nxt], g);
    cur = nxt;
  }
  final_head_kernel<<<B_, 256, 0, stream>>>(g, W1, b1, W2, b2, out);
}

// Round 12
// 765.545 us; speedup vs baseline: 1.2246x; 1.0750x over previous
//
#include <hip/hip_runtime.h>
#include <hip/hip_bf16.h>
#include <math.h>

#define B_ 32
#define L_ 128
#define LP 130      // padded L (zero row before/after each batch)
#define E_ 300
#define EP 320      // padded E (%64)
#define H_ 512
#define DOUT_ 5
#define NSTEP 5
#define G7 3584     // 7H
#define KGATES 1856 // 1536 (hl|h|hr from hpad) + 320 (x padded)
#define KFI 512     // h only (g handled via gfi per-batch bias)

typedef __hip_bfloat16 bf16;
using bf16x8 = __attribute__((ext_vector_type(8))) __bf16;
using f32x4 = __attribute__((ext_vector_type(4))) float;

__device__ __forceinline__ void gload16(const void* g, void* l) {
  __builtin_amdgcn_global_load_lds(
      (const __attribute__((address_space(1))) void*)g,
      (__attribute__((address_space(3))) void*)l, 16, 0, 0);
}

// ---------------- small helpers ----------------
__global__ void fill_zero(float* __restrict__ p, int n) {
  int i = blockIdx.x * blockDim.x + threadIdx.x;
  if (i < n) p[i] = 0.f;
}

__global__ void mask_lens_kernel(const int* __restrict__ lengths,
                                 float* __restrict__ maskf,
                                 float* __restrict__ invlens) {
  int i = blockIdx.x * blockDim.x + threadIdx.x;
  if (i < B_ * L_) {
    int b = i >> 7, l = i & 127;
    maskf[i] = (l < lengths[b]) ? 1.f : 0.f;
    if (l == 0) invlens[b] = 1.f / fmaxf((float)lengths[b], 1.f);
  }
}

__global__ void embed_bf16_kernel(const int* __restrict__ tokens,
                                  const float* __restrict__ embed,
                                  bf16* __restrict__ xb) {
  int i = blockIdx.x * blockDim.x + threadIdx.x;  // B*L*EP
  if (i >= B_ * L_ * EP) return;
  int e = i % EP, bl = i / EP;
  float v = (e < E_) ? embed[(size_t)tokens[bl] * E_ + e] : 0.f;
  xb[i] = __float2bfloat16(v);
}

__global__ void fill_pad(bf16* __restrict__ hpad) {
  int i = blockIdx.x * blockDim.x + threadIdx.x;  // B*2*H
  if (i >= B_ * 2 * H_) return;
  int hh = i & (H_ - 1);
  int r = (i >> 9) & 1, b = i >> 10;
  hpad[((size_t)(b * LP + r * (LP - 1))) * H_ + hh] = __float2bfloat16(0.f);
}

// transpose + cast: Wt[n][k] = W[k][n]; grid (Kregion/64, Ncols/64).
__global__ __launch_bounds__(256) void transpose_to_bf16(
    const float* __restrict__ W, bf16* __restrict__ Wt, int Kreal, int Ncols,
    int dstStride) {
  __shared__ float tile[64][65];
  const int k0 = blockIdx.x * 64, n0 = blockIdx.y * 64;
  const int t = threadIdx.x;
  const int nn = t & 63, kk0 = t >> 6;
#pragma unroll
  for (int p = 0; p < 16; ++p) {
    int kk = kk0 + p * 4;
    int gk = k0 + kk;
    tile[kk][nn] = (gk < Kreal) ? W[(size_t)gk * Ncols + n0 + nn] : 0.f;
  }
  __syncthreads();
#pragma unroll
  for (int p = 0; p < 2; ++p) {
    int r = (t >> 3) + p * 32;
    int kb = (t & 7) * 8;
    union { ushort h[8]; uint4 v; } u;
#pragma unroll
    for (int e = 0; e < 8; ++e) {
      bf16 b = __float2bfloat16(tile[kb + e][r]);
      u.h[e] = *(ushort*)&b;
    }
    *(uint4*)&Wt[(size_t)(n0 + r) * dstStride + k0 + kb] = u.v;
  }
}

// ---------------- generic bf16 MFMA GEMM (init only), 128x128, BK=64 --------
// A linear [M][KP]; OUT: bf16 into hpad (+1 row), tanh + rowscale.
__global__ __launch_bounds__(256) void gemm_mfma_init(
    const bf16* __restrict__ A, const bf16* __restrict__ Bt,
    const float* __restrict__ bias, const float* __restrict__ rowscale,
    bf16* __restrict__ Cout, int N, int KP) {
  __shared__ ushort As[128 * 64];
  __shared__ ushort Bs[128 * 64];
  const int tid = threadIdx.x;
  const int lane = tid & 63;
  const int w = tid >> 6;
  const int wr = w >> 1, wc = w & 1;
  const int nbx = gridDim.x;
  const int nwg = nbx * gridDim.y;
  int id = blockIdx.y * nbx + blockIdx.x;
  if ((nwg & 7) == 0) { int q = nwg >> 3; id = (id & 7) * q + (id >> 3); }
  const int bxi = id % nbx, byi = id / nbx;
  const int rowBase = byi * 128, colBase = bxi * 128;
  const int l15 = lane & 15, l4 = lane >> 4;
  f32x4 acc[4][4] = {};

  const bf16* bP[4];
  const bf16* aP[4];
#pragma unroll
  for (int i = 0; i < 4; ++i) {
    int c = tid + 256 * i;
    int r = c >> 3;
    int ql = (c & 7) ^ (r & 7);
    bP[i] = Bt + (size_t)(colBase + r) * KP + ql * 8;
    aP[i] = A + (size_t)(rowBase + r) * KP + ql * 8;
  }

  const int nIter = KP >> 6;
  for (int t = 0; t < nIter; ++t) {
    int k0 = t * 64;
#pragma unroll
    for (int i = 0; i < 4; ++i) {
      gload16(aP[i] + k0, &As[(tid + 256 * i) * 8]);
      gload16(bP[i] + k0, &Bs[(tid + 256 * i) * 8]);
    }
    __syncthreads();
#pragma unroll
    for (int kh = 0; kh < 2; ++kh) {
      bf16x8 aF[4], bF[4];
#pragma unroll
      for (int m = 0; m < 4; ++m) {
        int row = wr * 64 + m * 16 + l15;
        aF[m] = *(const bf16x8*)&As[row * 64 +
                                    (((kh << 2) + l4) ^ (l15 & 7)) * 8];
      }
#pragma unroll
      for (int n = 0; n < 4; ++n) {
        int row = wc * 64 + n * 16 + l15;
        bF[n] = *(const bf16x8*)&Bs[row * 64 +
                                    (((kh << 2) + l4) ^ (l15 & 7)) * 8];
      }
#pragma unroll
      for (int m = 0; m < 4; ++m)
#pragma unroll
        for (int n = 0; n < 4; ++n)
          acc[m][n] = __builtin_amdgcn_mfma_f32_16x16x32_bf16(
              aF[m], bF[n], acc[m][n], 0, 0, 0);
    }
    __syncthreads();
  }

#pragma unroll
  for (int m = 0; m < 4; ++m) {
#pragma unroll
    for (int n = 0; n < 4; ++n) {
      int col = colBase + wc * 64 + n * 16 + l15;
      float bv = bias[col];
#pragma unroll
      for (int j = 0; j < 4; ++j) {
        int row = rowBase + wr * 64 + m * 16 + l4 * 4 + j;
        float v = tanhf(acc[m][n][j] + bv) * rowscale[row];
        size_t oi = ((size_t)((row >> 7) * LP + (row & 127) + 1)) * H_ + col;
        Cout[oi] = __float2bfloat16(v);
      }
    }
  }
}

// ---------------- gates GEMM: BM=64, BN=128, BK=64, with length skip --------
// grid (28, 64); byi covers a half-batch (64 l-rows). Blocks whose 64 rows
// are entirely beyond lengths[b] exit immediately (outputs never consumed:
// cell_mean multiplies by mask=0; stale/poison bf16 is finite -> safe).
__global__ __launch_bounds__(256) void gates_gemm(
    const bf16* __restrict__ hpad, const bf16* __restrict__ xb,
    const bf16* __restrict__ Wgt, const float* __restrict__ bias,
    const float* __restrict__ gg, const int* __restrict__ lengths,
    bf16* __restrict__ gatesb) {
  __shared__ ushort As[64 * 64];   // 8 KB
  __shared__ ushort Bs[128 * 64];  // 16 KB
  const int tid = threadIdx.x;
  const int lane = tid & 63;
  const int w = tid >> 6;
  // XCD swizzle: nwg = 28*64 = 1792, q = 224
  int id = blockIdx.y * 28 + blockIdx.x;
  id = (id & 7) * 224 + (id >> 3);
  const int bxi = id % 28, byi = id / 28;
  const int b = byi >> 1, lhalf = byi & 1;
  if (lhalf && lengths[b] <= 64) return;  // whole row-block masked
  const int rowBase = byi * 64;
  const int colBase = bxi * 128;
  const int l15 = lane & 15, l4 = lane >> 4;
  f32x4 acc[4][2] = {};

  const int hRowBase = b * LP + lhalf * 64;   // hpad row of h_{l-1} for l0
  const int blBase = b * L_ + lhalf * 64;     // xb row
  const bf16* aP[2];
  const bf16* xP[2];
  const bf16* bP[4];
#pragma unroll
  for (int i = 0; i < 2; ++i) {
    int c = tid + 256 * i;  // 0..511
    int r = c >> 3;         // 0..63
    int ql = (c & 7) ^ (r & 7);
    aP[i] = hpad + (size_t)(hRowBase + r) * H_ + ql * 8;
    xP[i] = xb + (size_t)(blBase + r) * EP + ql * 8;
  }
#pragma unroll
  for (int i = 0; i < 4; ++i) {
    int c = tid + 256 * i;  // 0..1023
    int r = c >> 3;         // 0..127
    int ql = (c & 7) ^ (r & 7);
    bP[i] = Wgt + (size_t)(colBase + r) * KGATES + ql * 8;
  }

  auto step_ = [&](const bf16* const* ap, int ko, int kb) {
#pragma unroll
    for (int i = 0; i < 2; ++i)
      gload16(ap[i] + ko, &As[(tid + 256 * i) * 8]);
#pragma unroll
    for (int i = 0; i < 4; ++i)
      gload16(bP[i] + kb, &Bs[(tid + 256 * i) * 8]);
    __syncthreads();
#pragma unroll
    for (int kh = 0; kh < 2; ++kh) {
      bf16x8 aF[4], bF[2];
#pragma unroll
      for (int m = 0; m < 4; ++m) {
        int row = m * 16 + l15;
        aF[m] = *(const bf16x8*)&As[row * 64 +
                                    (((kh << 2) + l4) ^ (l15 & 7)) * 8];
      }
#pragma unroll
      for (int n = 0; n < 2; ++n) {
        int row = w * 32 + n * 16 + l15;
        bF[n] = *(const bf16x8*)&Bs[row * 64 +
                                    (((kh << 2) + l4) ^ (l15 & 7)) * 8];
      }
#pragma unroll
      for (int m = 0; m < 4; ++m)
#pragma unroll
        for (int n = 0; n < 2; ++n)
          acc[m][n] = __builtin_amdgcn_mfma_f32_16x16x32_bf16(
              aF[m], bF[n], acc[m][n], 0, 0, 0);
    }
    __syncthreads();
  };

  for (int t = 0; t < 24; ++t) step_(aP, t * 64, t * 64);
  for (int t = 24; t < 29; ++t) step_(xP, (t - 24) * 64, t * 64);

#pragma unroll
  for (int m = 0; m < 4; ++m) {
#pragma unroll
    for (int n = 0; n < 2; ++n) {
      int col = colBase + w * 32 + n * 16 + l15;
      float bv = bias[col] + gg[(size_t)b * G7 + col];
      bf16 tmp[4];
#pragma unroll
      for (int j = 0; j < 4; ++j)
        tmp[j] = __float2bfloat16(acc[m][n][j] + bv);
      int row0 = rowBase + m * 16 + l4 * 4;
      *(uint2*)&gatesb[((size_t)(row0 >> 2) * G7 + col) * 4] = *(uint2*)tmp;
    }
  }
}

// ---------------- per-batch g-vector GEMMs: gg = g@Wg_g, gfi = g@Wfi_top ----
__global__ __launch_bounds__(256) void gvec_gemm(
    const float* __restrict__ g, const float* __restrict__ Wgg,
    const float* __restrict__ Wfi, float* __restrict__ gg,
    float* __restrict__ gfi) {
  __shared__ float vin[H_];
  __shared__ float red[4][64];
  const int b = blockIdx.y;
  for (int i = threadIdx.x; i < H_; i += 256) vin[i] = g[(size_t)b * H_ + i];
  __syncthreads();
  const int o = threadIdx.x & 63, kp = threadIdx.x >> 6;
  const bool isg = blockIdx.x < 56;
  const int n0 = isg ? blockIdx.x * 64 : (blockIdx.x - 56) * 64;
  const float* W = isg ? Wgg : Wfi;
  const int ldw = isg ? G7 : H_;
  float acc = 0.f;
#pragma unroll 4
  for (int k = kp * 128; k < kp * 128 + 128; ++k)
    acc = fmaf(vin[k], W[(size_t)k * ldw + n0 + o], acc);
  red[kp][o] = acc;
  __syncthreads();
  if (threadIdx.x < 64) {
    int t = threadIdx.x;
    float v = red[0][t] + red[1][t] + red[2][t] + red[3][t];
    if (isg) gg[(size_t)b * G7 + n0 + t] = v;
    else gfi[(size_t)b * H_ + n0 + t] = v;
  }
}

// ---------------- fused fi GEMM (K=512) + slot softmax, 64-col tiles --------
__global__ __launch_bounds__(256) void fi_slot_kernel(
    const bf16* __restrict__ hpad, const bf16* __restrict__ Wfit,
    const float* __restrict__ bfi, const float* __restrict__ gfi,
    const float* __restrict__ fg, const float* __restrict__ og,
    const bf16* __restrict__ c_new, const float* __restrict__ cg_old,
    const float* __restrict__ maskf, float* __restrict__ cg_new,
    float* __restrict__ g_new) {
  __shared__ __align__(16) char smem[64 * 129 * 4 + 3072];  // 36096 B
  ushort* As = (ushort*)smem;              // [128*64] staging (dead later)
  ushort* Bs = As + 128 * 64;              // [64*64]
  float* sfi = (float*)smem;               // [64 cols][129] after K-loop
  float* part = sfi + 64 * 129;            // [4][3][64]

  const int tid = threadIdx.x;
  const int lane = tid & 63;
  const int w = tid >> 6;                  // wave -> rows w*32..w*32+31
  const int b = blockIdx.y;
  const int colBase = blockIdx.x * 64;
  const int l15 = lane & 15, l4 = lane >> 4;
  f32x4 acc[2][4] = {};

  const bf16* aP[4];
  const bf16* bP[2];
#pragma unroll
  for (int i = 0; i < 4; ++i) {
    int c = tid + 256 * i;
    int r = c >> 3;
    int ql = (c & 7) ^ (r & 7);
    aP[i] = hpad + ((size_t)(b * LP + r + 1)) * H_ + ql * 8;
  }
#pragma unroll
  for (int i = 0; i < 2; ++i) {
    int c = tid + 256 * i;
    int r = c >> 3;
    int ql = (c & 7) ^ (r & 7);
    bP[i] = Wfit + (size_t)(colBase + r) * KFI + ql * 8;
  }

  for (int t = 0; t < 8; ++t) {
    int k0 = t * 64;
#pragma unroll
    for (int i = 0; i < 4; ++i)
      gload16(aP[i] + k0, &As[(tid + 256 * i) * 8]);
#pragma unroll
    for (int i = 0; i < 2; ++i)
      gload16(bP[i] + k0, &Bs[(tid + 256 * i) * 8]);
    __syncthreads();
#pragma unroll
    for (int kh = 0; kh < 2; ++kh) {
      bf16x8 aF[2], bF[4];
#pragma unroll
      for (int m = 0; m < 2; ++m) {
        int row = w * 32 + m * 16 + l15;
        aF[m] = *(const bf16x8*)&As[row * 64 +
                                    (((kh << 2) + l4) ^ (l15 & 7)) * 8];
      }
#pragma unroll
      for (int n = 0; n < 4; ++n) {
        int row = n * 16 + l15;
        bF[n] = *(const bf16x8*)&Bs[row * 64 +
                                    (((kh << 2) + l4) ^ (l15 & 7)) * 8];
      }
#pragma unroll
      for (int m = 0; m < 2; ++m)
#pragma unroll
        for (int n = 0; n < 4; ++n)
          acc[m][n] = __builtin_amdgcn_mfma_f32_16x16x32_bf16(
              aF[m], bF[n], acc[m][n], 0, 0, 0);
    }
    __syncthreads();
  }

  // fi tile -> LDS
#pragma unroll
  for (int m = 0; m < 2; ++m) {
#pragma unroll
    for (int n = 0; n < 4; ++n) {
      int hl_ = n * 16 + l15;
      float bv = bfi[colBase + hl_] + gfi[(size_t)b * H_ + colBase + hl_];
#pragma unroll
      for (int j = 0; j < 4; ++j) {
        int l = w * 32 + m * 16 + l4 * 4 + j;
        sfi[hl_ * 129 + l] = acc[m][n][j] + bv;
      }
    }
  }
  __syncthreads();

  // online softmax over slots: 4 threads per column, 32 l each
  {
    int h = tid & 63, q = tid >> 6;
    int hcol = colBase + h;
    const float* mp = maskf + b * L_;
    float m = -3.0e38f, s = 0.f, tv = 0.f;
    for (int l = q * 32; l < q * 32 + 32; ++l) {
      if (mp[l] > 0.f) {
        float xv = sfi[h * 129 + l];
        float vv = __bfloat162float(c_new[((size_t)(b * L_ + l)) * H_ + hcol]);
        float m2 = fmaxf(m, xv);
        float sc = expf(m - m2);
        float e = expf(xv - m2);
        s = s * sc + e;
        tv = tv * sc + e * vv;
        m = m2;
      }
    }
    part[q * 192 + h] = m;
    part[q * 192 + 64 + h] = s;
    part[q * 192 + 128 + h] = tv;
  }
  __syncthreads();
  if (tid < 64) {
    int hcol = colBase + tid;
    int i0 = b * H_ + hcol;
    float mm = part[tid], s0 = part[64 + tid], t0 = part[128 + tid];
#pragma unroll
    for (int k = 1; k < 4; ++k) {
      float mk = part[k * 192 + tid];
      float m2 = fmaxf(mm, mk);
      float e1 = expf(mm - m2), e2 = expf(mk - m2);
      s0 = s0 * e1 + part[k * 192 + 64 + tid] * e2;
      t0 = t0 * e1 + part[k * 192 + 128 + tid] * e2;
      mm = m2;
    }
    float f = fg[i0];
    float m2 = fmaxf(mm, f);
    float ea = expf(mm - m2), eb = expf(f - m2);
    s0 = s0 * ea + eb;
    t0 = t0 * ea + cg_old[i0] * eb;
    float cgn = t0 / s0;
    float gn = og[i0] * tanhf(cgn);
    cg_new[i0] = cgn;
    g_new[i0] = gn;
  }
}

// ---------------- fused cell update + h-mean (uint2-coalesced, bf16 c) ------
__global__ __launch_bounds__(512) void cell_mean_kernel(
    const bf16* __restrict__ gates, const bf16* __restrict__ c_old,
    const float* __restrict__ cg_old, const float* __restrict__ maskf,
    const float* __restrict__ invlens, bf16* __restrict__ hpad,
    bf16* __restrict__ c_new, float* __restrict__ havg) {
  __shared__ float part[8][64];
  const int b = blockIdx.y;
  const int h0 = blockIdx.x * 64;
  const int hh = threadIdx.x & 63;
  const int lq = threadIdx.x >> 6;  // 0..7
  const int hcol = h0 + hh;
  const float cgv = cg_old[b * H_ + hcol];
  float s = 0.f;
  for (int it = 0; it < 4; ++it) {
    const int gi = it * 8 + lq;     // 4-row group 0..31
    const int l0 = gi * 4;
    const size_t gbase = ((size_t)(b * 32 + gi) * G7 + hcol) * 4;
    uint2 gv[7];
#pragma unroll
    for (int gt = 0; gt < 7; ++gt)
      gv[gt] = *(const uint2*)&gates[gbase + (size_t)gt * H_ * 4];
    float crow[6];
#pragma unroll
    for (int jj = 0; jj < 6; ++jj) {
      int l = l0 + jj - 1;
      crow[jj] = (l >= 0 && l < L_)
                     ? __bfloat162float(c_old[((size_t)(b * L_ + l)) * H_ + hcol])
                     : 0.f;
    }
#pragma unroll
    for (int j = 0; j < 4; ++j) {
      int l = l0 + j;
      int bl = b * L_ + l;
      float gl_[7];
#pragma unroll
      for (int gt = 0; gt < 7; ++gt) {
        ushort us = ((const ushort*)&gv[gt])[j];
        bf16 hb;
        *(ushort*)&hb = us;
        gl_[gt] = __bfloat162float(hb);
      }
      float m = fmaxf(fmaxf(fmaxf(gl_[0], gl_[1]), fmaxf(gl_[2], gl_[3])),
                      gl_[4]);
      float ei = expf(gl_[0] - m), el = expf(gl_[1] - m),
            ef = expf(gl_[2] - m), er = expf(gl_[3] - m),
            es = expf(gl_[4] - m);
      float inv = 1.f / (ei + el + ef + er + es);
      float o = 1.f / (1.f + expf(-gl_[5]));
      float u = tanhf(gl_[6]);
      float mk = maskf[bl];
      float cn = (el * crow[j] + ef * crow[j + 1] + er * crow[j + 2] +
                  es * cgv + ei * u) * inv * mk;
      float hn = o * tanhf(cn) * mk;
      c_new[(size_t)bl * H_ + hcol] = __float2bfloat16(cn);
      hpad[((size_t)(b * LP + l + 1)) * H_ + hcol] = __float2bfloat16(hn);
      s += hn;
    }
  }
  part[lq][hh] = s;
  __syncthreads();
  if (threadIdx.x < 64) {
    int t = threadIdx.x;
    float v = 0.f;
#pragma unroll
    for (int k = 0; k < 8; ++k) v += part[k][t];
    havg[b * H_ + h0 + t] = v * invlens[b];
  }
}

// deterministic parallel mean over L from bf16 hpad (init only)
__global__ __launch_bounds__(256) void reduce_mean_v2(
    const bf16* __restrict__ hpad, const float* __restrict__ invlens,
    float* __restrict__ outf) {
  __shared__ float sm[4][64];
  int b = blockIdx.y, h0 = blockIdx.x * 64;
  int lg = threadIdx.x >> 6, hh = threadIdx.x & 63;
  float s = 0.f;
  for (int l = lg * 32; l < lg * 32 + 32; ++l)
    s += __bfloat162float(hpad[((size_t)(b * LP + l + 1)) * H_ + h0 + hh]);
  sm[lg][hh] = s;
  __syncthreads();
  if (threadIdx.x < 64) {
    int t = threadIdx.x;
    outf[b * H_ + h0 + t] =
        (sm[0][t] + sm[1][t] + sm[2][t] + sm[3][t]) * invlens[b];
  }
}

// ---------------- batched vector GEMM (z-muxed two outputs) -----------------
__global__ __launch_bounds__(256) void batch_vec_gemm(
    const float* __restrict__ in1, int K1, const float* __restrict__ in2,
    int K2, const float* __restrict__ Wa, const float* __restrict__ ba,
    float* __restrict__ outa, int acta, const float* __restrict__ Wb,
    const float* __restrict__ bb, float* __restrict__ outb, int actb, int N) {
  const float* W = (blockIdx.z == 0) ? Wa : Wb;
  const float* bias = (blockIdx.z == 0) ? ba : bb;
  float* op = (blockIdx.z == 0) ? outa : outb;
  int act = (blockIdx.z == 0) ? acta : actb;
  __shared__ float vin[1024];
  __shared__ float red[4][64];
  const int K = K1 + K2;
  const int n0 = blockIdx.x * 64, b = blockIdx.y;
  for (int i = threadIdx.x; i < K; i += 256)
    vin[i] = (i < K1) ? in1[(size_t)b * K1 + i]
                      : in2[(size_t)b * K2 + (i - K1)];
  __syncthreads();
  const int o = threadIdx.x & 63, kp = threadIdx.x >> 6;
  float acc = 0.f;
  const int kc = K >> 2;
#pragma unroll 4
  for (int k = kp * kc; k < kp * kc + kc; ++k)
    acc = fmaf(vin[k], W[(size_t)k * N + n0 + o], acc);
  red[kp][o] = acc;
  __syncthreads();
  if (threadIdx.x < 64) {
    int t = threadIdx.x;
    float v = red[0][t] + red[1][t] + red[2][t] + red[3][t] + bias[n0 + t];
    if (act == 1) v = 1.f / (1.f + expf(-v));
    else if (act == 2) v = tanhf(v);
    op[(size_t)b * N + n0 + t] = v;
  }
}

// ---------------- fused final head -------------------------------------------
__global__ __launch_bounds__(256) void final_head_kernel(
    const float* __restrict__ g, const float* __restrict__ W1,
    const float* __restrict__ b1, const float* __restrict__ W2,
    const float* __restrict__ b2, float* __restrict__ out) {
  __shared__ float gv[H_];
  __shared__ float t1s[2 * H_];
  __shared__ float red[256][6];
  const int b = blockIdx.x;
  const int tid = threadIdx.x;
  for (int i = tid; i < H_; i += 256) gv[i] = g[b * H_ + i];
  __syncthreads();
  float accp[4];
#pragma unroll
  for (int p = 0; p < 4; ++p) accp[p] = b1[tid + p * 256];
  for (int k = 0; k < H_; ++k) {
    float gk = gv[k];
#pragma unroll
    for (int p = 0; p < 4; ++p)
      accp[p] = fmaf(gk, W1[(size_t)k * (2 * H_) + tid + p * 256], accp[p]);
  }
#pragma unroll
  for (int p = 0; p < 4; ++p) t1s[tid + p * 256] = tanhf(accp[p]);
  __syncthreads();
  float pd[DOUT_] = {0.f, 0.f, 0.f, 0.f, 0.f};
#pragma unroll
  for (int p = 0; p < 4; ++p) {
    int j = tid + p * 256;
    float tv = t1s[j];
#pragma unroll
    for (int d = 0; d < DOUT_; ++d)
      pd[d] = fmaf(tv, W2[(size_t)j * DOUT_ + d], pd[d]);
  }
#pragma unroll
  for (int d = 0; d < DOUT_; ++d) red[tid][d] = pd[d];
  __syncthreads();
  for (int stride = 128; stride >= 1; stride >>= 1) {
    if (tid < stride) {
#pragma unroll
      for (int d = 0; d < DOUT_; ++d) red[tid][d] += red[tid + stride][d];
    }
    __syncthreads();
  }
  if (tid == 0) {
    float lg[DOUT_];
#pragma unroll
    for (int d = 0; d < DOUT_; ++d) lg[d] = red[0][d] + b2[d];
    float m = lg[0];
#pragma unroll
    for (int d = 1; d < DOUT_; ++d) m = fmaxf(m, lg[d]);
    float s = 0.f;
#pragma unroll
    for (int d = 0; d < DOUT_; ++d) s += expf(lg[d] - m);
    float ls = logf(s);
#pragma unroll
    for (int d = 0; d < DOUT_; ++d) out[b * DOUT_ + d] = lg[d] - m - ls;
  }
}

// ---------------- host ----------------
extern "C" void kernel_launch(void* const* d_in, const int* in_sizes, int n_in,
                              void* d_out, int out_size, void* d_ws,
                              size_t ws_size, hipStream_t stream) {
  (void)in_sizes; (void)n_in; (void)out_size; (void)ws_size;
  const int* tokens = (const int*)d_in[0];
  const int* lengths = (const int*)d_in[1];
  const float* embed = (const float*)d_in[2];
  const float* W0 = (const float*)d_in[3];
  const float* b0 = (const float*)d_in[4];
  const float* Wg = (const float*)d_in[5];
  const float* bg = (const float*)d_in[6];
  const float* Wgf = (const float*)d_in[7];
  const float* bgf = (const float*)d_in[8];
  const float* Wfi = (const float*)d_in[9];
  const float* bfi = (const float*)d_in[10];
  const float* Wgo = (const float*)d_in[11];
  const float* bgo = (const float*)d_in[12];
  const float* W1 = (const float*)d_in[13];
  const float* b1 = (const float*)d_in[14];
  const float* W2 = (const float*)d_in[15];
  const float* b2 = (const float*)d_in[16];
  float* out = (float*)d_out;

  float* ws = (float*)d_ws;
  size_t off = 0;
  auto alloc = [&](size_t nf) {
    float* p = ws + off;
    off += (nf + 7) & ~(size_t)7;
    return p;
  };
  bf16* xb = (bf16*)alloc((size_t)B_ * L_ * EP / 2);       // [4096][320]
  float* maskf = alloc(B_ * L_);
  float* invlens = alloc(B_);
  bf16* hpad = (bf16*)alloc((size_t)B_ * LP * H_ / 2);     // [32][130][512]
  bf16* cb0 = (bf16*)alloc((size_t)B_ * L_ * H_ / 2);      // bf16 c
  bf16* cb1 = (bf16*)alloc((size_t)B_ * L_ * H_ / 2);
  float* g = alloc(B_ * H_);
  float* cgb0 = alloc(B_ * H_);
  float* cgb1 = alloc(B_ * H_);
  float* havg = alloc(B_ * H_);
  float* fg = alloc(B_ * H_);
  float* og = alloc(B_ * H_);
  float* gg = alloc((size_t)B_ * G7);                      // [32][3584]
  float* gfi = alloc(B_ * H_);                             // [32][512]
  bf16* gatesb = (bf16*)alloc((size_t)B_ * L_ * G7 / 2);   // perm layout
  bf16* Wgt = (bf16*)alloc((size_t)G7 * KGATES / 2);       // [3584][1856]
  bf16* W0t = (bf16*)alloc((size_t)H_ * EP / 2);           // [512][320]
  bf16* Wfit = (bf16*)alloc((size_t)H_ * KFI / 2);         // [512][512]

  // ---- init ----
  mask_lens_kernel<<<(B_ * L_ + 255) / 256, 256, 0, stream>>>(lengths, maskf,
                                                              invlens);
  embed_bf16_kernel<<<(B_ * L_ * EP + 255) / 256, 256, 0, stream>>>(tokens,
                                                                    embed, xb);
  transpose_to_bf16<<<dim3(24, G7 / 64), 256, 0, stream>>>(Wg, Wgt, 1536, G7,
                                                           KGATES);
  transpose_to_bf16<<<dim3(5, G7 / 64), 256, 0, stream>>>(
      Wg + (size_t)1536 * G7, Wgt + 1536, 300, G7, KGATES);
  transpose_to_bf16<<<dim3(5, H_ / 64), 256, 0, stream>>>(W0, W0t, 300, H_, EP);
  transpose_to_bf16<<<dim3(8, H_ / 64), 256, 0, stream>>>(
      Wfi + (size_t)H_ * H_, Wfit, H_, H_, KFI);  // bottom 512 rows (h part)
  fill_pad<<<(B_ * 2 * H_ + 255) / 256, 256, 0, stream>>>(hpad);
  // h0 = tanh(xb @ W0 + b0) * mask -> hpad
  gemm_mfma_init<<<dim3(H_ / 128, (B_ * L_) / 128), 256, 0, stream>>>(
      xb, W0t, b0, maskf, hpad, H_, EP);
  reduce_mean_v2<<<dim3(8, B_), 256, 0, stream>>>(hpad, invlens, g);
  fill_zero<<<(B_ * L_ * H_ / 2 + 255) / 256, 256, 0, stream>>>(
      (float*)cb0, B_ * L_ * H_ / 2);
  fill_zero<<<(B_ * H_ + 255) / 256, 256, 0, stream>>>(cgb0, B_ * H_);

  bf16* cb[2] = {cb0, cb1};
  float* cgb[2] = {cgb0, cgb1};
  int cur = 0;
  for (int step = 0; step < NSTEP; ++step) {
    int nxt = cur ^ 1;
    // per-batch g contributions (gg for gates, gfi for fi)
    gvec_gemm<<<dim3(64, B_), 256, 0, stream>>>(g, Wg + (size_t)1836 * G7,
                                                Wfi, gg, gfi);
    // gates = [hl|h|hr|x] @ Wgt^T + bg + gg[b]  (perm bf16 out, length-skip)
    gates_gemm<<<dim3(28, 64), 256, 0, stream>>>(hpad, xb, Wgt, bg, gg,
                                                 lengths, gatesb);
    cell_mean_kernel<<<dim3(H_ / 64, B_), 512, 0, stream>>>(
        gatesb, cb[cur], cgb[cur], maskf, invlens, hpad, cb[nxt], havg);
    batch_vec_gemm<<<dim3(8, B_, 2), 256, 0, stream>>>(
        g, H_, havg, H_, Wgf, bgf, fg, 0, Wgo, bgo, og, 1, H_);
    fi_slot_kernel<<<dim3(H_ / 64, B_), 256, 0, stream>>>(
        hpad, Wfit, bfi, gfi, fg, og, cb[nxt], cgb[cur], maskf, cgb[nxt], g);
    cur = nxt;
  }
  final_head_kernel<<<B_, 256, 0, stream>>>(g, W1, b1, W2, b2, out);
}

// Round 13
// 708.601 us; speedup vs baseline: 1.3230x; 1.0804x over previous
//
#include <hip/hip_runtime.h>
#include <hip/hip_bf16.h>
#include <math.h>

#define B_ 32
#define L_ 128
#define LP 130      // padded L (zero row before/after each batch)
#define E_ 300
#define EP 320      // padded E (%64)
#define H_ 512
#define DOUT_ 5
#define NSTEP 5
#define G7 3584     // 7H
#define KGATES 1856 // 1536 (hl|h|hr from hpad) + 320 (x padded)
#define KFI 512     // h only (g handled via gfi per-batch bias)

typedef __hip_bfloat16 bf16;
using bf16x8 = __attribute__((ext_vector_type(8))) __bf16;
using f32x4 = __attribute__((ext_vector_type(4))) float;

__device__ __forceinline__ void gload16(const void* g, void* l) {
  __builtin_amdgcn_global_load_lds(
      (const __attribute__((address_space(1))) void*)g,
      (__attribute__((address_space(3))) void*)l, 16, 0, 0);
}

// ---------------- small helpers ----------------
__global__ void fill_zero(float* __restrict__ p, int n) {
  int i = blockIdx.x * blockDim.x + threadIdx.x;
  if (i < n) p[i] = 0.f;
}

__global__ void mask_lens_kernel(const int* __restrict__ lengths,
                                 float* __restrict__ maskf,
                                 float* __restrict__ invlens) {
  int i = blockIdx.x * blockDim.x + threadIdx.x;
  if (i < B_ * L_) {
    int b = i >> 7, l = i & 127;
    maskf[i] = (l < lengths[b]) ? 1.f : 0.f;
    if (l == 0) invlens[b] = 1.f / fmaxf((float)lengths[b], 1.f);
  }
}

__global__ void embed_bf16_kernel(const int* __restrict__ tokens,
                                  const float* __restrict__ embed,
                                  bf16* __restrict__ xb) {
  int i = blockIdx.x * blockDim.x + threadIdx.x;  // B*L*EP
  if (i >= B_ * L_ * EP) return;
  int e = i % EP, bl = i / EP;
  float v = (e < E_) ? embed[(size_t)tokens[bl] * E_ + e] : 0.f;
  xb[i] = __float2bfloat16(v);
}

__global__ void fill_pad2(bf16* __restrict__ hpad0, bf16* __restrict__ hpad1) {
  int i = blockIdx.x * blockDim.x + threadIdx.x;  // B*2*H
  if (i >= B_ * 2 * H_) return;
  int hh = i & (H_ - 1);
  int r = (i >> 9) & 1, b = i >> 10;
  size_t oi = ((size_t)(b * LP + r * (LP - 1))) * H_ + hh;
  hpad0[oi] = __float2bfloat16(0.f);
  hpad1[oi] = __float2bfloat16(0.f);
}

// transpose + cast: Wt[n][k] = W[k][n]; grid (Kregion/64, Ncols/64).
__global__ __launch_bounds__(256) void transpose_to_bf16(
    const float* __restrict__ W, bf16* __restrict__ Wt, int Kreal, int Ncols,
    int dstStride) {
  __shared__ float tile[64][65];
  const int k0 = blockIdx.x * 64, n0 = blockIdx.y * 64;
  const int t = threadIdx.x;
  const int nn = t & 63, kk0 = t >> 6;
#pragma unroll
  for (int p = 0; p < 16; ++p) {
    int kk = kk0 + p * 4;
    int gk = k0 + kk;
    tile[kk][nn] = (gk < Kreal) ? W[(size_t)gk * Ncols + n0 + nn] : 0.f;
  }
  __syncthreads();
#pragma unroll
  for (int p = 0; p < 2; ++p) {
    int r = (t >> 3) + p * 32;
    int kb = (t & 7) * 8;
    union { ushort h[8]; uint4 v; } u;
#pragma unroll
    for (int e = 0; e < 8; ++e) {
      bf16 b = __float2bfloat16(tile[kb + e][r]);
      u.h[e] = *(ushort*)&b;
    }
    *(uint4*)&Wt[(size_t)(n0 + r) * dstStride + k0 + kb] = u.v;
  }
}

// ---------------- init GEMM: 128x128, BK=64, tanh+mask -> hpad ---------------
__global__ __launch_bounds__(256) void gemm_mfma_init(
    const bf16* __restrict__ A, const bf16* __restrict__ Bt,
    const float* __restrict__ bias, const float* __restrict__ rowscale,
    bf16* __restrict__ Cout, int N, int KP) {
  __shared__ ushort As[128 * 64];
  __shared__ ushort Bs[128 * 64];
  const int tid = threadIdx.x;
  const int lane = tid & 63;
  const int w = tid >> 6;
  const int wr = w >> 1, wc = w & 1;
  const int nbx = gridDim.x;
  const int nwg = nbx * gridDim.y;
  int id = blockIdx.y * nbx + blockIdx.x;
  if ((nwg & 7) == 0) { int q = nwg >> 3; id = (id & 7) * q + (id >> 3); }
  const int bxi = id % nbx, byi = id / nbx;
  const int rowBase = byi * 128, colBase = bxi * 128;
  const int l15 = lane & 15, l4 = lane >> 4;
  f32x4 acc[4][4] = {};

  const bf16* bP[4];
  const bf16* aP[4];
#pragma unroll
  for (int i = 0; i < 4; ++i) {
    int c = tid + 256 * i;
    int r = c >> 3;
    int ql = (c & 7) ^ (r & 7);
    bP[i] = Bt + (size_t)(colBase + r) * KP + ql * 8;
    aP[i] = A + (size_t)(rowBase + r) * KP + ql * 8;
  }

  const int nIter = KP >> 6;
  for (int t = 0; t < nIter; ++t) {
    int k0 = t * 64;
#pragma unroll
    for (int i = 0; i < 4; ++i) {
      gload16(aP[i] + k0, &As[(tid + 256 * i) * 8]);
      gload16(bP[i] + k0, &Bs[(tid + 256 * i) * 8]);
    }
    __syncthreads();
#pragma unroll
    for (int kh = 0; kh < 2; ++kh) {
      bf16x8 aF[4], bF[4];
#pragma unroll
      for (int m = 0; m < 4; ++m) {
        int row = wr * 64 + m * 16 + l15;
        aF[m] = *(const bf16x8*)&As[row * 64 +
                                    (((kh << 2) + l4) ^ (l15 & 7)) * 8];
      }
#pragma unroll
      for (int n = 0; n < 4; ++n) {
        int row = wc * 64 + n * 16 + l15;
        bF[n] = *(const bf16x8*)&Bs[row * 64 +
                                    (((kh << 2) + l4) ^ (l15 & 7)) * 8];
      }
#pragma unroll
      for (int m = 0; m < 4; ++m)
#pragma unroll
        for (int n = 0; n < 4; ++n)
          acc[m][n] = __builtin_amdgcn_mfma_f32_16x16x32_bf16(
              aF[m], bF[n], acc[m][n], 0, 0, 0);
    }
    __syncthreads();
  }

#pragma unroll
  for (int m = 0; m < 4; ++m) {
#pragma unroll
    for (int n = 0; n < 4; ++n) {
      int col = colBase + wc * 64 + n * 16 + l15;
      float bv = bias[col];
#pragma unroll
      for (int j = 0; j < 4; ++j) {
        int row = rowBase + wr * 64 + m * 16 + l4 * 4 + j;
        float v = tanhf(acc[m][n][j] + bv) * rowscale[row];
        size_t oi = ((size_t)((row >> 7) * LP + (row & 127) + 1)) * H_ + col;
        Cout[oi] = __float2bfloat16(v);
      }
    }
  }
}

// ---------------- fused gates GEMM + cell update + h-mean -------------------
// BM=64 (half-batch), BN=112 (16 h x 7 gates), BK=64, K=1856.
// grid (32, 64), XCD column-chunk swizzle: each XCD owns exactly 4 bxi
// (Wgt slice 1.66 MB -> L2-resident). B-row pointers apply the gate-major ->
// h-major permutation at address setup (src = (j%7)*512 + j/7).
// Epilogue: acc -> LDS, per-(l,h) 5-way gate softmax + cell update in fp32,
// writes c_new/hpad_new (bf16) + per-block h-sums to havg_part[lhalf][b][h].
// Blocks with lhalf==1 && len<=64 exit early (outputs masked / never read
// beyond negligible poison-tiny contributions; deterministic).
__global__ __launch_bounds__(256) void gates_cell_kernel(
    const bf16* __restrict__ hpad_old, const bf16* __restrict__ xb,
    const bf16* __restrict__ Wgt, const float* __restrict__ bg,
    const float* __restrict__ gg, const int* __restrict__ lengths,
    const bf16* __restrict__ c_old, const float* __restrict__ cg_old,
    bf16* __restrict__ c_new, bf16* __restrict__ hpad_new,
    float* __restrict__ havg_part) {
  __shared__ __align__(16) char smem[64 * 113 * 4 + 16 * 16 * 4];  // 29952 B
  ushort* As = (ushort*)smem;            // [64*64]  (K-loop)
  ushort* Bs = As + 64 * 64;             // [112*64] (K-loop)
  float* sfi = (float*)smem;             // [64][113] (epilogue)
  float* red = sfi + 64 * 113;           // [16][16]

  const int tid = threadIdx.x;
  const int lane = tid & 63;
  const int w = tid >> 6;
  int worig = blockIdx.y * 32 + blockIdx.x;
  int id = (worig & 7) * 256 + (worig >> 3);  // nwg=2048, bijective
  const int bxi = id >> 6;   // 0..31 -> column block (XCD-local)
  const int byi = id & 63;   // 0..63 -> half-batch
  const int b = byi >> 1, lhalf = byi & 1;
  const int len = lengths[b];
  if (lhalf && len <= 64) return;
  const int l15 = lane & 15, l4 = lane >> 4;
  f32x4 acc[7] = {};

  const int hRowBase = b * LP + lhalf * 64;
  const int blBase = b * L_ + lhalf * 64;
  const bf16* aP[2];
  const bf16* xP[2];
  const bf16* bP[4];
#pragma unroll
  for (int i = 0; i < 2; ++i) {
    int c = tid + 256 * i;  // 0..511
    int r = c >> 3;         // 0..63
    int ql = (c & 7) ^ (r & 7);
    aP[i] = hpad_old + (size_t)(hRowBase + r) * H_ + ql * 8;
    xP[i] = xb + (size_t)(blBase + r) * EP + ql * 8;
  }
#pragma unroll
  for (int i = 0; i < 4; ++i) {
    int c = tid + 256 * i;  // 0..1023 (only <896 used)
    int r = (c < 896) ? (c >> 3) : 0;  // 0..111
    int ql = (c & 7) ^ (r & 7);
    int j = bxi * 112 + r;              // h-major col index
    int src = (j % 7) * 512 + (j / 7);  // natural gate-major Wg col
    bP[i] = Wgt + (size_t)src * KGATES + ql * 8;
  }

  auto step_ = [&](const bf16* const* ap, int ko, int kb) {
#pragma unroll
    for (int i = 0; i < 2; ++i)
      gload16(ap[i] + ko, &As[(tid + 256 * i) * 8]);
#pragma unroll
    for (int i = 0; i < 3; ++i)
      gload16(bP[i] + kb, &Bs[(tid + 256 * i) * 8]);
    if (tid < 128) gload16(bP[3] + kb, &Bs[(tid + 768) * 8]);
    __syncthreads();
#pragma unroll
    for (int kh = 0; kh < 2; ++kh) {
      int arow = w * 16 + l15;
      bf16x8 aF = *(const bf16x8*)&As[arow * 64 +
                                      (((kh << 2) + l4) ^ (l15 & 7)) * 8];
      bf16x8 bF[7];
#pragma unroll
      for (int n = 0; n < 7; ++n) {
        int brow = n * 16 + l15;
        bF[n] = *(const bf16x8*)&Bs[brow * 64 +
                                    (((kh << 2) + l4) ^ (l15 & 7)) * 8];
      }
#pragma unroll
      for (int n = 0; n < 7; ++n)
        acc[n] = __builtin_amdgcn_mfma_f32_16x16x32_bf16(aF, bF[n], acc[n],
                                                         0, 0, 0);
    }
    __syncthreads();
  };

  for (int t = 0; t < 24; ++t) step_(aP, t * 64, t * 64);
  for (int t = 24; t < 29; ++t) step_(xP, (t - 24) * 64, t * 64);

  // acc -> LDS: sfi[l_loc][n*16 + l15], rows l_loc = w*16 + l4*4 + j
#pragma unroll
  for (int n = 0; n < 7; ++n)
#pragma unroll
    for (int j = 0; j < 4; ++j)
      sfi[(w * 16 + l4 * 4 + j) * 113 + n * 16 + l15] = acc[n][j];
  __syncthreads();

  // cell update: thread -> h_loc = tid&15, l-group = tid>>4 (4 l's over its)
  const int hloc = tid & 15;
  const int lgrp = tid >> 4;
  const int hglob = bxi * 16 + hloc;
  float bv[7];
#pragma unroll
  for (int g = 0; g < 7; ++g)
    bv[g] = bg[g * 512 + hglob] + gg[(size_t)b * G7 + g * 512 + hglob];
  const float cgv = cg_old[b * H_ + hglob];
  float s = 0.f;
#pragma unroll
  for (int it = 0; it < 4; ++it) {
    int loc = lgrp + it * 16;        // 0..63
    int lglob = lhalf * 64 + loc;
    int bl = b * L_ + lglob;
    size_t coi = (size_t)bl * H_ + hglob;
    size_t hoi = ((size_t)(b * LP + lglob + 1)) * H_ + hglob;
    if (lglob >= len) {
      c_new[coi] = __float2bfloat16(0.f);
      hpad_new[hoi] = __float2bfloat16(0.f);
      continue;
    }
    float gl_[7];
#pragma unroll
    for (int g = 0; g < 7; ++g) gl_[g] = sfi[loc * 113 + hloc * 7 + g] + bv[g];
    float m = fmaxf(fmaxf(fmaxf(gl_[0], gl_[1]), fmaxf(gl_[2], gl_[3])),
                    gl_[4]);
    float ei = expf(gl_[0] - m), el = expf(gl_[1] - m), ef = expf(gl_[2] - m),
          er = expf(gl_[3] - m), es = expf(gl_[4] - m);
    float inv = 1.f / (ei + el + ef + er + es);
    float o = 1.f / (1.f + expf(-gl_[5]));
    float u = tanhf(gl_[6]);
    float cprev = (lglob >= 1)
                      ? __bfloat162float(c_old[coi - H_]) : 0.f;
    float ccur = __bfloat162float(c_old[coi]);
    float cnext = (lglob < L_ - 1)
                      ? __bfloat162float(c_old[coi + H_]) : 0.f;
    float cn = (el * cprev + ef * ccur + er * cnext + es * cgv + ei * u) * inv;
    float hn = o * tanhf(cn);
    c_new[coi] = __float2bfloat16(cn);
    hpad_new[hoi] = __float2bfloat16(hn);
    s += hn;
  }
  red[hloc * 16 + lgrp] = s;
  __syncthreads();
  if (tid < 16) {
    float v = 0.f;
#pragma unroll
    for (int k = 0; k < 16; ++k) v += red[tid * 16 + k];
    havg_part[(size_t)lhalf * B_ * H_ + (size_t)b * H_ + bxi * 16 + tid] = v;
  }
}

// ---------------- per-batch g-vector GEMMs: gg = g@Wg_g, gfi = g@Wfi_top ----
__global__ __launch_bounds__(256) void gvec_gemm(
    const float* __restrict__ g, const float* __restrict__ Wgg,
    const float* __restrict__ Wfi, float* __restrict__ gg,
    float* __restrict__ gfi) {
  __shared__ float vin[H_];
  __shared__ float red[4][64];
  const int b = blockIdx.y;
  for (int i = threadIdx.x; i < H_; i += 256) vin[i] = g[(size_t)b * H_ + i];
  __syncthreads();
  const int o = threadIdx.x & 63, kp = threadIdx.x >> 6;
  const bool isg = blockIdx.x < 56;
  const int n0 = isg ? blockIdx.x * 64 : (blockIdx.x - 56) * 64;
  const float* W = isg ? Wgg : Wfi;
  const int ldw = isg ? G7 : H_;
  float acc = 0.f;
#pragma unroll 4
  for (int k = kp * 128; k < kp * 128 + 128; ++k)
    acc = fmaf(vin[k], W[(size_t)k * ldw + n0 + o], acc);
  red[kp][o] = acc;
  __syncthreads();
  if (threadIdx.x < 64) {
    int t = threadIdx.x;
    float v = red[0][t] + red[1][t] + red[2][t] + red[3][t];
    if (isg) gg[(size_t)b * G7 + n0 + t] = v;
    else gfi[(size_t)b * H_ + n0 + t] = v;
  }
}

// ---------------- fg/og from (g, havg parts): grid (8, B, 2) ----------------
__global__ __launch_bounds__(256) void gnode_vec(
    const float* __restrict__ g, const float* __restrict__ havg_part,
    const float* __restrict__ invlens, const float* __restrict__ Wgf,
    const float* __restrict__ bgf, float* __restrict__ fg,
    const float* __restrict__ Wgo, const float* __restrict__ bgo,
    float* __restrict__ og) {
  const int z = blockIdx.z;
  const float* W = z ? Wgo : Wgf;
  const float* bias = z ? bgo : bgf;
  float* op = z ? og : fg;
  __shared__ float vin[1024];
  __shared__ float red[4][64];
  const int n0 = blockIdx.x * 64, b = blockIdx.y;
  const float il = invlens[b];
  for (int i = threadIdx.x; i < 1024; i += 256)
    vin[i] = (i < 512) ? g[(size_t)b * H_ + i]
                       : (havg_part[(size_t)b * H_ + (i - 512)] +
                          havg_part[(size_t)(B_ + b) * H_ + (i - 512)]) * il;
  __syncthreads();
  const int o = threadIdx.x & 63, kp = threadIdx.x >> 6;
  float acc = 0.f;
#pragma unroll 4
  for (int k = kp * 256; k < kp * 256 + 256; ++k)
    acc = fmaf(vin[k], W[(size_t)k * H_ + n0 + o], acc);
  red[kp][o] = acc;
  __syncthreads();
  if (threadIdx.x < 64) {
    int t = threadIdx.x;
    float v = red[0][t] + red[1][t] + red[2][t] + red[3][t] + bias[n0 + t];
    if (z) v = 1.f / (1.f + expf(-v));
    op[(size_t)b * H_ + n0 + t] = v;
  }
}

// ---------------- fused fi GEMM (K=512) + slot softmax, 64-col tiles --------
__global__ __launch_bounds__(256) void fi_slot_kernel(
    const bf16* __restrict__ hpad, const bf16* __restrict__ Wfit,
    const float* __restrict__ bfi, const float* __restrict__ gfi,
    const float* __restrict__ fg, const float* __restrict__ og,
    const bf16* __restrict__ c_new, const float* __restrict__ cg_old,
    const float* __restrict__ maskf, const int* __restrict__ lengths,
    float* __restrict__ cg_new, float* __restrict__ g_new) {
  __shared__ __align__(16) char smem[64 * 129 * 4 + 3072];  // 36096 B
  ushort* As = (ushort*)smem;              // [128*64] staging (dead later)
  ushort* Bs = As + 128 * 64;              // [64*64]
  float* sfi = (float*)smem;               // [64 cols][129] after K-loop
  float* part = sfi + 64 * 129;            // [4][3][64]

  const int tid = threadIdx.x;
  const int lane = tid & 63;
  const int w = tid >> 6;                  // wave -> rows w*32..w*32+31
  const int b = blockIdx.y;
  const int len = lengths[b];
  const bool wactive = len > w * 32;
  const int colBase = blockIdx.x * 64;
  const int l15 = lane & 15, l4 = lane >> 4;
  f32x4 acc[2][4] = {};

  const bf16* aP[4];
  const bf16* bP[2];
#pragma unroll
  for (int i = 0; i < 4; ++i) {
    int c = tid + 256 * i;
    int r = c >> 3;
    int ql = (c & 7) ^ (r & 7);
    aP[i] = hpad + ((size_t)(b * LP + r + 1)) * H_ + ql * 8;
  }
#pragma unroll
  for (int i = 0; i < 2; ++i) {
    int c = tid + 256 * i;
    int r = c >> 3;
    int ql = (c & 7) ^ (r & 7);
    bP[i] = Wfit + (size_t)(colBase + r) * KFI + ql * 8;
  }

  for (int t = 0; t < 8; ++t) {
    int k0 = t * 64;
#pragma unroll
    for (int i = 0; i < 4; ++i)
      gload16(aP[i] + k0, &As[(tid + 256 * i) * 8]);
#pragma unroll
    for (int i = 0; i < 2; ++i)
      gload16(bP[i] + k0, &Bs[(tid + 256 * i) * 8]);
    __syncthreads();
    if (wactive) {
#pragma unroll
      for (int kh = 0; kh < 2; ++kh) {
        bf16x8 aF[2], bF[4];
#pragma unroll
        for (int m = 0; m < 2; ++m) {
          int row = w * 32 + m * 16 + l15;
          aF[m] = *(const bf16x8*)&As[row * 64 +
                                      (((kh << 2) + l4) ^ (l15 & 7)) * 8];
        }
#pragma unroll
        for (int n = 0; n < 4; ++n) {
          int row = n * 16 + l15;
          bF[n] = *(const bf16x8*)&Bs[row * 64 +
                                      (((kh << 2) + l4) ^ (l15 & 7)) * 8];
        }
#pragma unroll
        for (int m = 0; m < 2; ++m)
#pragma unroll
          for (int n = 0; n < 4; ++n)
            acc[m][n] = __builtin_amdgcn_mfma_f32_16x16x32_bf16(
                aF[m], bF[n], acc[m][n], 0, 0, 0);
      }
    }
    __syncthreads();
  }

  // fi tile -> LDS (only active waves; inactive rows never read)
  if (wactive) {
#pragma unroll
    for (int m = 0; m < 2; ++m) {
#pragma unroll
      for (int n = 0; n < 4; ++n) {
        int hl_ = n * 16 + l15;
        float bv = bfi[colBase + hl_] + gfi[(size_t)b * H_ + colBase + hl_];
#pragma unroll
        for (int j = 0; j < 4; ++j) {
          int l = w * 32 + m * 16 + l4 * 4 + j;
          sfi[hl_ * 129 + l] = acc[m][n][j] + bv;
        }
      }
    }
  }
  __syncthreads();

  // online softmax over slots: 4 threads per column, 32 l each
  {
    int h = tid & 63, q = tid >> 6;
    int hcol = colBase + h;
    const float* mp = maskf + b * L_;
    float m = -3.0e38f, s = 0.f, tv = 0.f;
    if (len > q * 32) {
      for (int l = q * 32; l < q * 32 + 32; ++l) {
        if (mp[l] > 0.f) {
          float xv = sfi[h * 129 + l];
          float vv =
              __bfloat162float(c_new[((size_t)(b * L_ + l)) * H_ + hcol]);
          float m2 = fmaxf(m, xv);
          float sc = expf(m - m2);
          float e = expf(xv - m2);
          s = s * sc + e;
          tv = tv * sc + e * vv;
          m = m2;
        }
      }
    }
    part[q * 192 + h] = m;
    part[q * 192 + 64 + h] = s;
    part[q * 192 + 128 + h] = tv;
  }
  __syncthreads();
  if (tid < 64) {
    int hcol = colBase + tid;
    int i0 = b * H_ + hcol;
    float mm = part[tid], s0 = part[64 + tid], t0 = part[128 + tid];
#pragma unroll
    for (int k = 1; k < 4; ++k) {
      float mk = part[k * 192 + tid];
      float m2 = fmaxf(mm, mk);
      float e1 = expf(mm - m2), e2 = expf(mk - m2);
      s0 = s0 * e1 + part[k * 192 + 64 + tid] * e2;
      t0 = t0 * e1 + part[k * 192 + 128 + tid] * e2;
      mm = m2;
    }
    float f = fg[i0];
    float m2 = fmaxf(mm, f);
    float ea = expf(mm - m2), eb = expf(f - m2);
    s0 = s0 * ea + eb;
    t0 = t0 * ea + cg_old[i0] * eb;
    float cgn = t0 / s0;
    float gn = og[i0] * tanhf(cgn);
    cg_new[i0] = cgn;
    g_new[i0] = gn;
  }
}

// deterministic parallel mean over L from bf16 hpad (init only)
__global__ __launch_bounds__(256) void reduce_mean_v2(
    const bf16* __restrict__ hpad, const float* __restrict__ invlens,
    float* __restrict__ outf) {
  __shared__ float sm[4][64];
  int b = blockIdx.y, h0 = blockIdx.x * 64;
  int lg = threadIdx.x >> 6, hh = threadIdx.x & 63;
  float s = 0.f;
  for (int l = lg * 32; l < lg * 32 + 32; ++l)
    s += __bfloat162float(hpad[((size_t)(b * LP + l + 1)) * H_ + h0 + hh]);
  sm[lg][hh] = s;
  __syncthreads();
  if (threadIdx.x < 64) {
    int t = threadIdx.x;
    outf[b * H_ + h0 + t] =
        (sm[0][t] + sm[1][t] + sm[2][t] + sm[3][t]) * invlens[b];
  }
}

// ---------------- fused final head -------------------------------------------
__global__ __launch_bounds__(256) void final_head_kernel(
    const float* __restrict__ g, const float* __restrict__ W1,
    const float* __restrict__ b1, const float* __restrict__ W2,
    const float* __restrict__ b2, float* __restrict__ out) {
  __shared__ float gv[H_];
  __shared__ float t1s[2 * H_];
  __shared__ float red[256][6];
  const int b = blockIdx.x;
  const int tid = threadIdx.x;
  for (int i = tid; i < H_; i += 256) gv[i] = g[b * H_ + i];
  __syncthreads();
  float accp[4];
#pragma unroll
  for (int p = 0; p < 4; ++p) accp[p] = b1[tid + p * 256];
  for (int k = 0; k < H_; ++k) {
    float gk = gv[k];
#pragma unroll
    for (int p = 0; p < 4; ++p)
      accp[p] = fmaf(gk, W1[(size_t)k * (2 * H_) + tid + p * 256], accp[p]);
  }
#pragma unroll
  for (int p = 0; p < 4; ++p) t1s[tid + p * 256] = tanhf(accp[p]);
  __syncthreads();
  float pd[DOUT_] = {0.f, 0.f, 0.f, 0.f, 0.f};
#pragma unroll
  for (int p = 0; p < 4; ++p) {
    int j = tid + p * 256;
    float tv = t1s[j];
#pragma unroll
    for (int d = 0; d < DOUT_; ++d)
      pd[d] = fmaf(tv, W2[(size_t)j * DOUT_ + d], pd[d]);
  }
#pragma unroll
  for (int d = 0; d < DOUT_; ++d) red[tid][d] = pd[d];
  __syncthreads();
  for (int stride = 128; stride >= 1; stride >>= 1) {
    if (tid < stride) {
#pragma unroll
      for (int d = 0; d < DOUT_; ++d) red[tid][d] += red[tid + stride][d];
    }
    __syncthreads();
  }
  if (tid == 0) {
    float lg[DOUT_];
#pragma unroll
    for (int d = 0; d < DOUT_; ++d) lg[d] = red[0][d] + b2[d];
    float m = lg[0];
#pragma unroll
    for (int d = 1; d < DOUT_; ++d) m = fmaxf(m, lg[d]);
    float s = 0.f;
#pragma unroll
    for (int d = 0; d < DOUT_; ++d) s += expf(lg[d] - m);
    float ls = logf(s);
#pragma unroll
    for (int d = 0; d < DOUT_; ++d) out[b * DOUT_ + d] = lg[d] - m - ls;
  }
}

// ---------------- host ----------------
extern "C" void kernel_launch(void* const* d_in, const int* in_sizes, int n_in,
                              void* d_out, int out_size, void* d_ws,
                              size_t ws_size, hipStream_t stream) {
  (void)in_sizes; (void)n_in; (void)out_size; (void)ws_size;
  const int* tokens = (const int*)d_in[0];
  const int* lengths = (const int*)d_in[1];
  const float* embed = (const float*)d_in[2];
  const float* W0 = (const float*)d_in[3];
  const float* b0 = (const float*)d_in[4];
  const float* Wg = (const float*)d_in[5];
  const float* bg = (const float*)d_in[6];
  const float* Wgf = (const float*)d_in[7];
  const float* bgf = (const float*)d_in[8];
  const float* Wfi = (const float*)d_in[9];
  const float* bfi = (const float*)d_in[10];
  const float* Wgo = (const float*)d_in[11];
  const float* bgo = (const float*)d_in[12];
  const float* W1 = (const float*)d_in[13];
  const float* b1 = (const float*)d_in[14];
  const float* W2 = (const float*)d_in[15];
  const float* b2 = (const float*)d_in[16];
  float* out = (float*)d_out;

  float* ws = (float*)d_ws;
  size_t off = 0;
  auto alloc = [&](size_t nf) {
    float* p = ws + off;
    off += (nf + 7) & ~(size_t)7;
    return p;
  };
  bf16* xb = (bf16*)alloc((size_t)B_ * L_ * EP / 2);       // [4096][320]
  float* maskf = alloc(B_ * L_);
  float* invlens = alloc(B_);
  bf16* hpad0 = (bf16*)alloc((size_t)B_ * LP * H_ / 2);    // [32][130][512]
  bf16* hpad1 = (bf16*)alloc((size_t)B_ * LP * H_ / 2);
  bf16* cb0 = (bf16*)alloc((size_t)B_ * L_ * H_ / 2);      // bf16 c
  bf16* cb1 = (bf16*)alloc((size_t)B_ * L_ * H_ / 2);
  float* g = alloc(B_ * H_);
  float* cgb0 = alloc(B_ * H_);
  float* cgb1 = alloc(B_ * H_);
  float* havg_part = alloc((size_t)2 * B_ * H_);           // [2][32][512]
  float* fg = alloc(B_ * H_);
  float* og = alloc(B_ * H_);
  float* gg = alloc((size_t)B_ * G7);                      // [32][3584]
  float* gfi = alloc(B_ * H_);                             // [32][512]
  bf16* Wgt = (bf16*)alloc((size_t)G7 * KGATES / 2);       // [3584][1856]
  bf16* W0t = (bf16*)alloc((size_t)H_ * EP / 2);           // [512][320]
  bf16* Wfit = (bf16*)alloc((size_t)H_ * KFI / 2);         // [512][512]

  // ---- init ----
  mask_lens_kernel<<<(B_ * L_ + 255) / 256, 256, 0, stream>>>(lengths, maskf,
                                                              invlens);
  embed_bf16_kernel<<<(B_ * L_ * EP + 255) / 256, 256, 0, stream>>>(tokens,
                                                                    embed, xb);
  transpose_to_bf16<<<dim3(24, G7 / 64), 256, 0, stream>>>(Wg, Wgt, 1536, G7,
                                                           KGATES);
  transpose_to_bf16<<<dim3(5, G7 / 64), 256, 0, stream>>>(
      Wg + (size_t)1536 * G7, Wgt + 1536, 300, G7, KGATES);
  transpose_to_bf16<<<dim3(5, H_ / 64), 256, 0, stream>>>(W0, W0t, 300, H_, EP);
  transpose_to_bf16<<<dim3(8, H_ / 64), 256, 0, stream>>>(
      Wfi + (size_t)H_ * H_, Wfit, H_, H_, KFI);  // bottom 512 rows (h part)
  fill_pad2<<<(B_ * 2 * H_ + 255) / 256, 256, 0, stream>>>(hpad0, hpad1);
  // h0 = tanh(xb @ W0 + b0) * mask -> hpad0
  gemm_mfma_init<<<dim3(H_ / 128, (B_ * L_) / 128), 256, 0, stream>>>(
      xb, W0t, b0, maskf, hpad0, H_, EP);
  reduce_mean_v2<<<dim3(8, B_), 256, 0, stream>>>(hpad0, invlens, g);
  fill_zero<<<(B_ * L_ * H_ / 2 + 255) / 256, 256, 0, stream>>>(
      (float*)cb0, B_ * L_ * H_ / 2);
  fill_zero<<<(B_ * H_ + 255) / 256, 256, 0, stream>>>(cgb0, B_ * H_);
  fill_zero<<<(B_ * H_ + 255) / 256, 256, 0, stream>>>(havg_part + B_ * H_,
                                                       B_ * H_);

  bf16* cb[2] = {cb0, cb1};
  bf16* hp[2] = {hpad0, hpad1};
  float* cgb[2] = {cgb0, cgb1};
  int cur = 0;
  for (int step = 0; step < NSTEP; ++step) {
    int nxt = cur ^ 1;
    // per-batch g contributions (gg for gates, gfi for fi)
    gvec_gemm<<<dim3(64, B_), 256, 0, stream>>>(g, Wg + (size_t)1836 * G7,
                                                Wfi, gg, gfi);
    // gates GEMM + cell update + h-mean, fused
    gates_cell_kernel<<<dim3(32, 64), 256, 0, stream>>>(
        hp[cur], xb, Wgt, bg, gg, lengths, cb[cur], cgb[cur], cb[nxt],
        hp[nxt], havg_part);
    gnode_vec<<<dim3(8, B_, 2), 256, 0, stream>>>(
        g, havg_part, invlens, Wgf, bgf, fg, Wgo, bgo, og);
    fi_slot_kernel<<<dim3(8, B_), 256, 0, stream>>>(
        hp[nxt], Wfit, bfi, gfi, fg, og, cb[nxt], cgb[cur], maskf, lengths,
        cgb[nxt], g);
    cur = nxt;
  }
  final_head_kernel<<<B_, 256, 0, stream>>>(g, W1, b1, W2, b2, out);
}